// Round 6
// baseline (252.159 us; speedup 1.0000x reference)
//
#include <hip/hip_runtime.h>
#include <math.h>

// Problem dims
#define Bb 2
#define Tt 16
#define Hh 64
#define Ww 64
#define Cc 64
#define ST_ (Hh*Ww*Cc)    // 262144
#define SB_ (Tt*Hh*Ww*Cc) // 4194304

#define TWO_PI 6.2831853071795864769f

typedef __attribute__((ext_vector_type(8))) short bf16x8;
typedef __attribute__((ext_vector_type(4))) float f32x4;

// workspace u32-offsets: two ping-pong X buffers
#define BUF_A    0u
#define BUF_B    8388608u

__device__ __forceinline__ float2 cmul(float2 a, float2 b) {
    return make_float2(fmaf(a.x, b.x, -a.y * b.y), fmaf(a.x, b.y, a.y * b.x));
}
__device__ __forceinline__ float2 cadd(float2 a, float2 b) { return make_float2(a.x + b.x, a.y + b.y); }
__device__ __forceinline__ float2 csub(float2 a, float2 b) { return make_float2(a.x - b.x, a.y - b.y); }

// bf16 pair pack/unpack (x -> low 16, y -> high 16). RNE; range = fp32.
__device__ __forceinline__ unsigned bfpack(float2 f) {
    unsigned r = __float_as_uint(f.x);
    unsigned i = __float_as_uint(f.y);
    r = (r + 0x7fffu + ((r >> 16) & 1u)) >> 16;
    i = (i + 0x7fffu + ((i >> 16) & 1u)) >> 16;
    return r | (i << 16);
}
__device__ __forceinline__ float2 bfunpack(unsigned u) {
    return make_float2(__uint_as_float(u << 16), __uint_as_float(u & 0xffff0000u));
}

union U48 { uint4 u4; uint2 u2[2]; unsigned u[4]; bf16x8 v8; };

// ---------------------------------------------------------------------------
// In-register twiddle fragment builders (verified R4/R5).
// wp = r*16+m (A-row), k0 = ka*32 + q*8 + 2p.
// ---------------------------------------------------------------------------
__device__ __forceinline__ U48 tw_wf(int wp, int q, int ka, int reim) {
    U48 o;
#pragma unroll
    for (int p = 0; p < 4; ++p) {
        int k0 = ka * 32 + q * 8 + 2 * p;
        float v[2];
#pragma unroll
        for (int dk = 0; dk < 2; ++dk) {
            int k = k0 + dk;
            int a = (wp * k) & 63;
            float sn, cs; sincosf(TWO_PI * (float)a * (1.0f / 64.0f), &sn, &cs);
            v[dk] = reim ? -sn : cs;
        }
        o.u[p] = bfpack(make_float2(v[0], v[1]));
    }
    return o;
}

// tbl: 1 = fwd H (cpx K=128), 2 = inv H (cpx K=128, scale 1/64)
__device__ __forceinline__ U48 tw_cpx(int wp, int q, int ka, int reim, int tbl) {
    U48 o;
#pragma unroll
    for (int p = 0; p < 4; ++p) {
        int k0 = ka * 32 + q * 8 + 2 * p;
        float v[2];
#pragma unroll
        for (int dk = 0; dk < 2; ++dk) {
            int k = k0 + dk;
            int h = k >> 1;
            int a = (wp * h) & 63;
            float sn, cs; sincosf(TWO_PI * (float)a * (1.0f / 64.0f), &sn, &cs);
            bool even = (k & 1) == 0;
            float vv;
            if (tbl == 1) vv = reim ? (even ? -sn : cs) : (even ? cs : sn);
            else          vv = (reim ? (even ? sn : cs) : (even ? cs : -sn)) * (1.0f / 64.0f);
            v[dk] = vv;
        }
        o.u[p] = bfpack(make_float2(v[0], v[1]));
    }
    return o;
}

// inv W, real output, scale 1/64
__device__ __forceinline__ U48 tw_wi(int wp, int q, int ka) {
    U48 o;
#pragma unroll
    for (int p = 0; p < 4; ++p) {
        int k0 = ka * 32 + q * 8 + 2 * p;
        float v[2];
#pragma unroll
        for (int dk = 0; dk < 2; ++dk) {
            int k = k0 + dk;
            int h = k >> 1;
            int a = (wp * h) & 63;
            float sn, cs; sincosf(TWO_PI * (float)a * (1.0f / 64.0f), &sn, &cs);
            bool even = (k & 1) == 0;
            v[dk] = (even ? cs : -sn) * (1.0f / 64.0f);
        }
        o.u[p] = bfpack(make_float2(v[0], v[1]));
    }
    return o;
}

// LDS index for the 256-col x 64-pt Z buffer (64 KB): same XOR family as R4/R5.
__device__ __forceinline__ int zidx(int col, int h) {
    return (col << 6) + (h ^ (((col >> 1) & 7) << 3));
}

template <int S>
__device__ __forceinline__ void fft4(float2& a, float2& b, float2& c, float2& d) {
    float2 t0 = cadd(a, c), t1 = csub(a, c);
    float2 t2 = cadd(b, d), t3 = csub(b, d);
    a = cadd(t0, t2);
    c = csub(t0, t2);
    b = make_float2(t1.x - (float)S * t3.y, t1.y + (float)S * t3.x);
    d = make_float2(t1.x + (float)S * t3.y, t1.y - (float)S * t3.x);
}

// 16-pt FFT in registers, natural order in/out, radix 4x4.
template <int S>
__device__ __forceinline__ void fft16(float2 v[16]) {
    const float CS[10] = {1.f, 0.92387953f, 0.70710678f, 0.38268343f, 0.f,
                          -0.38268343f, -0.70710678f, -0.92387953f, -1.f, -0.92387953f};
    const float SN[10] = {0.f, 0.38268343f, 0.70710678f, 0.92387953f, 1.f,
                          0.92387953f, 0.70710678f, 0.38268343f, 0.f, -0.38268343f};
    float2 A[4][4];
#pragma unroll
    for (int j = 0; j < 4; ++j) {
        A[j][0] = v[j]; A[j][1] = v[4 + j]; A[j][2] = v[8 + j]; A[j][3] = v[12 + j];
        fft4<S>(A[j][0], A[j][1], A[j][2], A[j][3]);
#pragma unroll
        for (int k0 = 0; k0 < 4; ++k0) {
            int m = j * k0;
            float2 tw = make_float2(CS[m], (float)S * SN[m]);
            A[j][k0] = cmul(A[j][k0], tw);
        }
    }
#pragma unroll
    for (int k0 = 0; k0 < 4; ++k0) {
        fft4<S>(A[0][k0], A[1][k0], A[2][k0], A[3][k0]);
        v[k0] = A[0][k0]; v[k0 + 4] = A[1][k0]; v[k0 + 8] = A[2][k0]; v[k0 + 12] = A[3][k0];
    }
}

// ---------------------------------------------------------------------------
// K1: fused forward 2D DFT-64x64. wg = (b,t,c4): grid 512, 512 thr = 8 waves
// (2 teams x 4 row-quarters). LDS 72 KB -> 2 wg/CU. All chunk data preloaded
// to registers (8 float4) before the chunk loop. Stage 1: W-DFT (real K=64)
// -> Z[(w'*4+c)][h]. Stage 2: H-DFT (cpx K=128) from Z -> X2 (b,h,w,t,c).
// ---------------------------------------------------------------------------
__global__ __launch_bounds__(512, 4) void k_fwd2d(const float* __restrict__ x,
                                                  unsigned* __restrict__ X2) {
    __shared__ unsigned Z[256 * 64];     // 64 KB
    __shared__ unsigned P[4 * 16 * 32];  // 8 KB chunk: [c4][h16][w2]
    int tid = threadIdx.x;
    int lane = tid & 63, r = (tid >> 6) & 3, team = tid >> 8;
    int m = lane & 15, q = lane >> 4;
    int wg = blockIdx.x;               // (b,t,c4-group): 2*16*16 = 512
    int bt = wg >> 4;
    int c0 = (wg & 15) * 4;
    int b = wg >> 8, t = (wg >> 4) & 15;
    const float* xs = x + (size_t)bt * 262144;   // (h,w,c) slab
    int wp = r * 16 + m;
    int hme = m >> 2, cme = m & 3;

    // stage-1 twiddles
    U48 Are[2], Aim[2];
#pragma unroll
    for (int ka = 0; ka < 2; ++ka) { Are[ka] = tw_wf(wp, q, ka, 0); Aim[ka] = tw_wf(wp, q, ka, 1); }

    // preload ALL chunks: one pair-site (h, w2) per thread per chunk
    int s_h = tid >> 5;            // hloc 0..15
    int s_w2 = tid & 31;           // w2 0..31
    float4 f[4][2];
#pragma unroll
    for (int ch = 0; ch < 4; ++ch) {
        const float* pa = xs + (size_t)(ch * 16 + s_h) * 4096 + (size_t)s_w2 * 128 + c0;
        f[ch][0] = *(const float4*)pa;
        f[ch][1] = *(const float4*)(pa + 64);
    }

    for (int ch = 0; ch < 4; ++ch) {
        int h = ch * 16 + s_h;
        float a0[4] = {f[ch][0].x, f[ch][0].y, f[ch][0].z, f[ch][0].w};
        float a1[4] = {f[ch][1].x, f[ch][1].y, f[ch][1].z, f[ch][1].w};
#pragma unroll
        for (int j = 0; j < 4; ++j) {
            int w2s = s_w2 ^ ((((h & 3) ^ ((j & 1) << 1))) << 3);
            P[j * 512 + s_h * 32 + w2s] = bfpack(make_float2(a0[j], a1[j]));
        }
        __syncthreads();
        // compute: 4 g-groups this chunk (2 per team); g covers 4 h x 4 c
#pragma unroll
        for (int gi = 0; gi < 2; ++gi) {
            int g = ch * 4 + gi * 2 + team;
            int h2 = g * 4 + hme;
            int hl2 = h2 & 15;
            int swz = ((h2 & 3) ^ ((cme & 1) << 1)) << 3;
            U48 B[2];
#pragma unroll
            for (int ka = 0; ka < 2; ++ka) {
                int w2a = (ka * 16 + q * 4) ^ swz;
                B[ka].u4 = *(const uint4*)&P[cme * 512 + hl2 * 32 + w2a];
            }
            f32x4 ar = {0.f, 0.f, 0.f, 0.f}, ai = {0.f, 0.f, 0.f, 0.f};
#pragma unroll
            for (int ka = 0; ka < 2; ++ka) {
                ar = __builtin_amdgcn_mfma_f32_16x16x32_bf16(Are[ka].v8, B[ka].v8, ar, 0, 0, 0);
                ai = __builtin_amdgcn_mfma_f32_16x16x32_bf16(Aim[ka].v8, B[ka].v8, ai, 0, 0, 0);
            }
#pragma unroll
            for (int reg = 0; reg < 4; ++reg) {
                int wpp = r * 16 + q * 4 + reg;
                Z[zidx(wpp * 4 + cme, h2)] = bfpack(make_float2(ar[reg], ai[reg]));
            }
        }
        __syncthreads();
    }

    // stage 2: H-DFT (cpx K=128) from Z -> X2
    U48 Hre[4], Him[4];
#pragma unroll
    for (int ka = 0; ka < 4; ++ka) { Hre[ka] = tw_cpx(wp, q, ka, 0, 1); Him[ka] = tw_cpx(wp, q, ka, 1, 1); }
    size_t ob = (size_t)b * 4194304 + (size_t)t * 64 + (c0 + cme);
#pragma unroll 2
    for (int gi = 0; gi < 8; ++gi) {
        int g = gi * 2 + team;
        int col = g * 16 + m;          // = w*4 + cL
        int w = g * 4 + hme;
        U48 B[4];
#pragma unroll
        for (int ka = 0; ka < 4; ++ka) {
            int h0 = ka * 16 + q * 4;
            int zi = zidx(col, h0);
            B[ka].u2[0] = *(const uint2*)&Z[zi];
            B[ka].u2[1] = *(const uint2*)&Z[zi + 2];
        }
        f32x4 ar = {0.f, 0.f, 0.f, 0.f}, ai = {0.f, 0.f, 0.f, 0.f};
#pragma unroll
        for (int ka = 0; ka < 4; ++ka) {
            ar = __builtin_amdgcn_mfma_f32_16x16x32_bf16(Hre[ka].v8, B[ka].v8, ar, 0, 0, 0);
            ai = __builtin_amdgcn_mfma_f32_16x16x32_bf16(Him[ka].v8, B[ka].v8, ai, 0, 0, 0);
        }
#pragma unroll
        for (int reg = 0; reg < 4; ++reg) {
            int hp = r * 16 + q * 4 + reg;
            X2[ob + (size_t)hp * 65536 + (size_t)w * 1024] = bfpack(make_float2(ar[reg], ai[reg]));
        }
    }
}

// ---------------------------------------------------------------------------
// K3: fused inverse 2D DFT. wg = (b,t,c4): grid 512. LDS 72 KB -> 2 wg/CU.
// All chunk data preloaded (8 uint4). Stage 1: H-inv (cpx K=128, 1/64) from
// P -> Z[(h'*4+c)][w]. Stage 2: W-inv (real out, 1/64) -> out fp32.
// ---------------------------------------------------------------------------
__global__ __launch_bounds__(512, 4) void k_inv2d(const unsigned* __restrict__ X3,
                                                  float* __restrict__ out) {
    __shared__ unsigned Z[256 * 64];     // 64 KB
    __shared__ unsigned P[4 * 8 * 64];   // 8 KB chunk: [c4][w8][h64]
    int tid = threadIdx.x;
    int lane = tid & 63, r = (tid >> 6) & 3, team = tid >> 8;
    int m = lane & 15, q = lane >> 4;
    int wg = blockIdx.x;
    int bt = wg >> 4;
    int c0 = (wg & 15) * 4;
    const unsigned* xs = X3 + (size_t)bt * 262144;   // (w,h,c) slab
    int wp = r * 16 + m;
    int hme = m >> 2, cme = m & 3;

    // stage-1 twiddles: H-inv
    U48 Hre[4], Him[4];
#pragma unroll
    for (int ka = 0; ka < 4; ++ka) { Hre[ka] = tw_cpx(wp, q, ka, 0, 2); Him[ka] = tw_cpx(wp, q, ka, 1, 2); }

    // preload ALL chunks: one (w,h) site per thread per chunk
    int s_wl = tid >> 6;           // 0..7
    int s_hh = tid & 63;           // 0..63
    uint4 d[8];
#pragma unroll
    for (int cw = 0; cw < 8; ++cw)
        d[cw] = *(const uint4*)(xs + (size_t)(cw * 8 + s_wl) * 4096 + (size_t)s_hh * 64 + c0);

    for (int cw = 0; cw < 8; ++cw) {
        unsigned dd[4] = {d[cw].x, d[cw].y, d[cw].z, d[cw].w};
#pragma unroll
        for (int j = 0; j < 4; ++j) {
            int hs = s_hh ^ ((((s_wl & 3) ^ ((j & 1) << 1))) << 3);
            P[j * 512 + s_wl * 64 + hs] = dd[j];
        }
        __syncthreads();
        // compute: 2 g-groups this chunk (1 per team); g covers 4 w x 4 c
        {
            int g = cw * 2 + team;
            int w = g * 4 + hme;
            int wl = w & 7;
            int swz = ((wl & 3) ^ ((cme & 1) << 1)) << 3;
            U48 B[4];
#pragma unroll
            for (int ka = 0; ka < 4; ++ka) {
                int ha = (ka * 16 + q * 4) ^ swz;
                B[ka].u4 = *(const uint4*)&P[cme * 512 + wl * 64 + ha];
            }
            f32x4 ar = {0.f, 0.f, 0.f, 0.f}, ai = {0.f, 0.f, 0.f, 0.f};
#pragma unroll
            for (int ka = 0; ka < 4; ++ka) {
                ar = __builtin_amdgcn_mfma_f32_16x16x32_bf16(Hre[ka].v8, B[ka].v8, ar, 0, 0, 0);
                ai = __builtin_amdgcn_mfma_f32_16x16x32_bf16(Him[ka].v8, B[ka].v8, ai, 0, 0, 0);
            }
#pragma unroll
            for (int reg = 0; reg < 4; ++reg) {
                int hp = r * 16 + q * 4 + reg;
                Z[zidx(hp * 4 + cme, w)] = bfpack(make_float2(ar[reg], ai[reg]));
            }
        }
        __syncthreads();
    }

    // stage 2: W-inv (real out)
    U48 Wre[4];
#pragma unroll
    for (int ka = 0; ka < 4; ++ka) Wre[ka] = tw_wi(wp, q, ka);
#pragma unroll 2
    for (int gi = 0; gi < 8; ++gi) {
        int g = gi * 2 + team;
        int col = g * 16 + m;          // = h*4 + cL
        int h = g * 4 + hme;
        U48 B[4];
#pragma unroll
        for (int ka = 0; ka < 4; ++ka) {
            int w0 = ka * 16 + q * 4;
            int zi = zidx(col, w0);
            B[ka].u2[0] = *(const uint2*)&Z[zi];
            B[ka].u2[1] = *(const uint2*)&Z[zi + 2];
        }
        f32x4 ar = {0.f, 0.f, 0.f, 0.f};
#pragma unroll
        for (int ka = 0; ka < 4; ++ka)
            ar = __builtin_amdgcn_mfma_f32_16x16x32_bf16(Wre[ka].v8, B[ka].v8, ar, 0, 0, 0);
        float* dst = out + (size_t)bt * 262144 + (size_t)h * 4096 + (c0 + cme);
#pragma unroll
        for (int reg = 0; reg < 4; ++reg) {
            int wpp = r * 16 + q * 4 + reg;
            dst[(size_t)wpp * 64] = ar[reg];
        }
    }
}

// ---------------------------------------------------------------------------
// K2 (mid): unchanged (verified R4/R5). FFT-16 fwd along T + gates + MFMA
// delta-matmul + scan + FFT-16 inv. X2 (b,h,w,t,c) -> X3 (b,t,w,h,c).
// ---------------------------------------------------------------------------
__global__ __launch_bounds__(256) void k_mid(
    const float* __restrict__ x, const unsigned* __restrict__ X2,
    unsigned* __restrict__ X3,
    const float* __restrict__ Ak, const float* __restrict__ Bk,
    const float* __restrict__ fb, const float* __restrict__ fs,
    const float* __restrict__ ib, const float* __restrict__ isc_,
    const float* __restrict__ dW, const float* __restrict__ db) {
    const float CT[16] = {1.f, 0.9238795f, 0.7071068f, 0.3826834f, 0.f, -0.3826834f,
                          -0.7071068f, -0.9238795f, -1.f, -0.9238795f, -0.7071068f,
                          -0.3826834f, 0.f, 0.3826834f, 0.7071068f, 0.9238795f};
    const float SN[16] = {0.f, 0.3826834f, 0.7071068f, 0.9238795f, 1.f, 0.9238795f,
                          0.7071068f, 0.3826834f, 0.f, -0.3826834f, -0.7071068f,
                          -0.9238795f, -1.f, -0.9238795f, -0.7071068f, -0.3826834f};
    __shared__ float Akl[1728], Bkl[1728];
    __shared__ __align__(16) float xs[4][16 * 68 + 4];

    int tid = threadIdx.x;
    int g = tid >> 6, lane = tid & 63;
    int c = lane;
    int m = lane & 15, q = lane >> 4;
    int site = blockIdx.x * 4 + g;
    int b = site >> 12, hw = site & 4095;
    int h = hw >> 6, w = hw & 63;
    size_t base = (size_t)b * SB_ + (size_t)hw * 64;

    for (int i = tid; i < 1728; i += 256) { Akl[i] = Ak[i]; Bkl[i] = Bk[i]; }

    // delta-W MFMA B-fragments in-register
    U48 Ub[4][2];
#pragma unroll
    for (int nt = 0; nt < 4; ++nt)
#pragma unroll
        for (int ka = 0; ka < 2; ++ka)
#pragma unroll
            for (int p2 = 0; p2 < 4; ++p2) {
                int kb = ka * 32 + q * 8 + 2 * p2;
                int ccol = m + 16 * nt;
                Ub[nt][ka].u[p2] = bfpack(make_float2(dW[kb * 64 + ccol], dW[(kb + 1) * 64 + ccol]));
            }

    float xv[16];
    float2 v[16];
    const unsigned* src2 = X2 + (size_t)site * 1024;
#pragma unroll
    for (int t = 0; t < 16; ++t) {
        xv[t] = x[base + (size_t)t * ST_ + c];
        v[t] = bfunpack(src2[t * 64 + c]);
    }
#pragma unroll
    for (int t = 0; t < 16; ++t) xs[g][t * 68 + c] = xv[t];
    __syncthreads();

    // MFMA delta matmul
    bf16x8 Afrag[2];
#pragma unroll
    for (int ka = 0; ka < 2; ++ka) {
        int d0 = ka * 32 + q * 8;
        const float* p = &xs[g][m * 68 + d0];
        float4 f0 = *(const float4*)p;
        float4 f1 = *(const float4*)(p + 4);
        union { bf16x8 v8; unsigned uu[4]; } U;
        U.uu[0] = bfpack(make_float2(f0.x, f0.y));
        U.uu[1] = bfpack(make_float2(f0.z, f0.w));
        U.uu[2] = bfpack(make_float2(f1.x, f1.y));
        U.uu[3] = bfpack(make_float2(f1.z, f1.w));
        Afrag[ka] = U.v8;
    }
#pragma unroll
    for (int nt = 0; nt < 4; ++nt) {
        int ccol = m + 16 * nt;
        float dbn = db[ccol];
        f32x4 acc = {dbn, dbn, dbn, dbn};
#pragma unroll
        for (int ka = 0; ka < 2; ++ka)
            acc = __builtin_amdgcn_mfma_f32_16x16x32_bf16(Afrag[ka], Ub[nt][ka].v8, acc, 0, 0, 0);
#pragma unroll
        for (int reg = 0; reg < 4; ++reg)
            xs[g][(q * 4 + reg) * 68 + ccol] = acc[reg];
    }

    // A_f/B_f generators from the 27 taps
    float sh, ch; sincosf(TWO_PI * (float)h / 64.0f, &sh, &ch);
    float sw, cw; sincosf(TWO_PI * (float)w / 64.0f, &sw, &cw);
    float2 eh[3] = { make_float2(ch, sh), make_float2(1.f, 0.f), make_float2(ch, -sh) };
    float2 ew[3] = { make_float2(cw, sw), make_float2(1.f, 0.f), make_float2(cw, -sw) };
    float2 GA[3], GB[3];
#pragma unroll
    for (int kt = 0; kt < 3; ++kt) { GA[kt] = make_float2(0.f, 0.f); GB[kt] = make_float2(0.f, 0.f); }
#pragma unroll
    for (int kh = 0; kh < 3; ++kh) {
#pragma unroll
        for (int kw = 0; kw < 3; ++kw) {
            float2 e = cmul(eh[kh], ew[kw]);
#pragma unroll
            for (int kt = 0; kt < 3; ++kt) {
                float ka = Akl[c * 27 + kt * 9 + kh * 3 + kw];
                float kb = Bkl[c * 27 + kt * 9 + kh * 3 + kw];
                GA[kt].x = fmaf(ka, e.x, GA[kt].x);
                GA[kt].y = fmaf(ka, e.y, GA[kt].y);
                GB[kt].x = fmaf(kb, e.x, GB[kt].x);
                GB[kt].y = fmaf(kb, e.y, GB[kt].y);
            }
        }
    }
    float fbc = fb[c], fsc = fs[c], ibc = ib[c], iscv = isc_[c];

    fft16<-1>(v);
    __syncthreads();

    float delta_raw[16];
#pragma unroll
    for (int t = 0; t < 16; ++t) delta_raw[t] = xs[g][t * 68 + c];

    float2 hv = make_float2(0.f, 0.f);
#pragma unroll
    for (int t = 0; t < 16; ++t) {
        float ct = CT[t], st = SN[t];
        float2 Af, Bf;
        Af.x = GA[1].x + ct * (GA[0].x + GA[2].x) - st * (GA[0].y - GA[2].y);
        Af.y = GA[1].y + ct * (GA[0].y + GA[2].y) + st * (GA[0].x - GA[2].x);
        Bf.x = GB[1].x + ct * (GB[0].x + GB[2].x) - st * (GB[0].y - GB[2].y);
        Bf.y = GB[1].y + ct * (GB[0].y + GB[2].y) + st * (GB[0].x - GB[2].x);

        float xc = xv[t];
        float fg  = __builtin_amdgcn_rcpf(1.f + __expf(-(fbc + fsc * xc)));
        float igv = __builtin_amdgcn_rcpf(1.f + __expf(-(ibc + iscv * xc)));
        float dot = delta_raw[t];
        float delta = (dot > 20.f) ? dot : __logf(1.f + __expf(dot));

        float sR = igv * delta;
        float2 bbv;
        bbv.x = sR * (Bf.x * v[t].x - Bf.y * v[t].y);
        bbv.y = sR * (Bf.x * v[t].y + Bf.y * v[t].x);
        float2 av = make_float2(fg * Af.x, fg * Af.y);
        float2 nh;
        nh.x = av.x * hv.x - av.y * hv.y + bbv.x;
        nh.y = av.x * hv.y + av.y * hv.x + bbv.y;
        hv = nh;
        v[t] = hv;
    }

    fft16<1>(v);

    // write X3 (b,t,w,h,c)
    size_t ob = (size_t)b * 4194304 + (size_t)w * 4096 + (size_t)h * 64 + c;
#pragma unroll
    for (int t = 0; t < 16; ++t) {
        float2 o = make_float2(v[t].x * 0.0625f, v[t].y * 0.0625f);
        X3[ob + (size_t)t * 262144] = bfpack(o);
    }
}

extern "C" void kernel_launch(void* const* d_in, const int* in_sizes, int n_in,
                              void* d_out, int out_size, void* d_ws, size_t ws_size,
                              hipStream_t stream) {
    const float* x   = (const float*)d_in[0];
    const float* Ak  = (const float*)d_in[1];
    const float* Bk  = (const float*)d_in[2];
    const float* fb  = (const float*)d_in[3];
    const float* fs  = (const float*)d_in[4];
    const float* ib  = (const float*)d_in[5];
    const float* is_ = (const float*)d_in[6];
    const float* dW  = (const float*)d_in[7];
    const float* db  = (const float*)d_in[8];
    float* out = (float*)d_out;
    unsigned* ws = (unsigned*)d_ws;
    unsigned* X2 = ws + BUF_A;
    unsigned* X3 = ws + BUF_B;

    k_fwd2d<<<Bb * Tt * 16, 512, 0, stream>>>(x, X2);
    k_mid<<<(Bb * Hh * Ww) / 4, 256, 0, stream>>>(x, X2, X3, Ak, Bk, fb, fs, ib, is_, dW, db);
    k_inv2d<<<Bb * Tt * 16, 512, 0, stream>>>(X3, out);
}

// Round 7
// 201.232 us; speedup vs baseline: 1.2531x; 1.2531x over previous
//
#include <hip/hip_runtime.h>
#include <math.h>

// Problem dims
#define Bb 2
#define Tt 16
#define Hh 64
#define Ww 64
#define Cc 64
#define ST_ (Hh*Ww*Cc)    // 262144
#define SB_ (Tt*Hh*Ww*Cc) // 4194304

#define TWO_PI 6.2831853071795864769f

typedef __attribute__((ext_vector_type(8))) short bf16x8;
typedef __attribute__((ext_vector_type(4))) float f32x4;

// workspace u32-offsets: two ping-pong X buffers
#define BUF_A    0u
#define BUF_B    8388608u

__device__ __forceinline__ float2 cmul(float2 a, float2 b) {
    return make_float2(fmaf(a.x, b.x, -a.y * b.y), fmaf(a.x, b.y, a.y * b.x));
}
__device__ __forceinline__ float2 cadd(float2 a, float2 b) { return make_float2(a.x + b.x, a.y + b.y); }
__device__ __forceinline__ float2 csub(float2 a, float2 b) { return make_float2(a.x - b.x, a.y - b.y); }

// bf16 pair pack/unpack (x -> low 16, y -> high 16). RNE; range = fp32.
__device__ __forceinline__ unsigned bfpack(float2 f) {
    unsigned r = __float_as_uint(f.x);
    unsigned i = __float_as_uint(f.y);
    r = (r + 0x7fffu + ((r >> 16) & 1u)) >> 16;
    i = (i + 0x7fffu + ((i >> 16) & 1u)) >> 16;
    return r | (i << 16);
}
__device__ __forceinline__ float2 bfunpack(unsigned u) {
    return make_float2(__uint_as_float(u << 16), __uint_as_float(u & 0xffff0000u));
}

union U48 { uint4 u4; uint2 u2[2]; unsigned u[4]; bf16x8 v8; };

// ---------------------------------------------------------------------------
// In-register twiddle fragment builders (verified R4/R5).
// wp = r*16+m (A-row), k0 = ka*32 + q*8 + 2p.
// ---------------------------------------------------------------------------
__device__ __forceinline__ U48 tw_wf(int wp, int q, int ka, int reim) {
    U48 o;
#pragma unroll
    for (int p = 0; p < 4; ++p) {
        int k0 = ka * 32 + q * 8 + 2 * p;
        float v[2];
#pragma unroll
        for (int dk = 0; dk < 2; ++dk) {
            int k = k0 + dk;
            int a = (wp * k) & 63;
            float sn, cs; sincosf(TWO_PI * (float)a * (1.0f / 64.0f), &sn, &cs);
            v[dk] = reim ? -sn : cs;
        }
        o.u[p] = bfpack(make_float2(v[0], v[1]));
    }
    return o;
}

// tbl: 1 = fwd H (cpx K=128), 2 = inv H (cpx K=128, scale 1/64)
__device__ __forceinline__ U48 tw_cpx(int wp, int q, int ka, int reim, int tbl) {
    U48 o;
#pragma unroll
    for (int p = 0; p < 4; ++p) {
        int k0 = ka * 32 + q * 8 + 2 * p;
        float v[2];
#pragma unroll
        for (int dk = 0; dk < 2; ++dk) {
            int k = k0 + dk;
            int h = k >> 1;
            int a = (wp * h) & 63;
            float sn, cs; sincosf(TWO_PI * (float)a * (1.0f / 64.0f), &sn, &cs);
            bool even = (k & 1) == 0;
            float vv;
            if (tbl == 1) vv = reim ? (even ? -sn : cs) : (even ? cs : sn);
            else          vv = (reim ? (even ? sn : cs) : (even ? cs : -sn)) * (1.0f / 64.0f);
            v[dk] = vv;
        }
        o.u[p] = bfpack(make_float2(v[0], v[1]));
    }
    return o;
}

// inv W, real output, scale 1/64
__device__ __forceinline__ U48 tw_wi(int wp, int q, int ka) {
    U48 o;
#pragma unroll
    for (int p = 0; p < 4; ++p) {
        int k0 = ka * 32 + q * 8 + 2 * p;
        float v[2];
#pragma unroll
        for (int dk = 0; dk < 2; ++dk) {
            int k = k0 + dk;
            int h = k >> 1;
            int a = (wp * h) & 63;
            float sn, cs; sincosf(TWO_PI * (float)a * (1.0f / 64.0f), &sn, &cs);
            bool even = (k & 1) == 0;
            v[dk] = (even ? cs : -sn) * (1.0f / 64.0f);
        }
        o.u[p] = bfpack(make_float2(v[0], v[1]));
    }
    return o;
}

// LDS index for the 512-col x 64-pt Z buffer (128 KB): verified in R4/R5.
__device__ __forceinline__ int zidx(int col, int h) {
    return (col << 6) + (h ^ (((col >> 1) & 7) << 3));
}

template <int S>
__device__ __forceinline__ void fft4(float2& a, float2& b, float2& c, float2& d) {
    float2 t0 = cadd(a, c), t1 = csub(a, c);
    float2 t2 = cadd(b, d), t3 = csub(b, d);
    a = cadd(t0, t2);
    c = csub(t0, t2);
    b = make_float2(t1.x - (float)S * t3.y, t1.y + (float)S * t3.x);
    d = make_float2(t1.x + (float)S * t3.y, t1.y - (float)S * t3.x);
}

// 16-pt FFT in registers, natural order in/out, radix 4x4.
template <int S>
__device__ __forceinline__ void fft16(float2 v[16]) {
    const float CS[10] = {1.f, 0.92387953f, 0.70710678f, 0.38268343f, 0.f,
                          -0.38268343f, -0.70710678f, -0.92387953f, -1.f, -0.92387953f};
    const float SN[10] = {0.f, 0.38268343f, 0.70710678f, 0.92387953f, 1.f,
                          0.92387953f, 0.70710678f, 0.38268343f, 0.f, -0.38268343f};
    float2 A[4][4];
#pragma unroll
    for (int j = 0; j < 4; ++j) {
        A[j][0] = v[j]; A[j][1] = v[4 + j]; A[j][2] = v[8 + j]; A[j][3] = v[12 + j];
        fft4<S>(A[j][0], A[j][1], A[j][2], A[j][3]);
#pragma unroll
        for (int k0 = 0; k0 < 4; ++k0) {
            int m = j * k0;
            float2 tw = make_float2(CS[m], (float)S * SN[m]);
            A[j][k0] = cmul(A[j][k0], tw);
        }
    }
#pragma unroll
    for (int k0 = 0; k0 < 4; ++k0) {
        fft4<S>(A[0][k0], A[1][k0], A[2][k0], A[3][k0]);
        v[k0] = A[0][k0]; v[k0 + 4] = A[1][k0]; v[k0 + 8] = A[2][k0]; v[k0 + 12] = A[3][k0];
    }
}

// ---------------------------------------------------------------------------
// K1: fused forward 2D DFT-64x64. wg = (b,t,c8), 512 thr = 8 waves
// (2 teams x 4 row-quarters). T14 async staging: ALL chunk loads issued
// up-front (16 float4/thread); per chunk only reg->LDS + compute remain.
// Stage 1: W-DFT -> Z[(w'*8+c)][h]. Stage 2: H-DFT from Z -> X2 (b,h,w,t,c).
// ---------------------------------------------------------------------------
__global__ __launch_bounds__(512) void k_fwd2d(const float* __restrict__ x,
                                               unsigned* __restrict__ X2) {
    __shared__ unsigned Z[512 * 64];     // 128 KB
    __shared__ unsigned P[8 * 16 * 32];  // 16 KB chunk: [c8][h16][w2]
    int tid = threadIdx.x;
    int lane = tid & 63, r = (tid >> 6) & 3, team = tid >> 8;
    int wv = tid >> 6;
    int m = lane & 15, q = lane >> 4;
    int wg = blockIdx.x;               // (b,t,c8): 2*16*8 = 256
    int bt = wg >> 3;
    int c0 = (wg & 7) * 8;
    int b = wg >> 7, t = (wg >> 3) & 15;
    const float* xs = x + (size_t)bt * 262144;   // (h,w,c) slab
    int wp = r * 16 + m;
    int hme = m >> 3, cme = m & 7;

    // stage-1 twiddles
    U48 Are[2], Aim[2];
#pragma unroll
    for (int ka = 0; ka < 2; ++ka) { Are[ka] = tw_wf(wp, q, ka, 0); Aim[ka] = tw_wf(wp, q, ka, 1); }

    // staging lane decode: per wave-instr covers 4h x 8w2 x 2cq
    int s_hl = lane >> 4;          // 0..3
    int s_p  = (lane >> 1) & 7;    // 0..7
    int s_cq = lane & 1;           // 0..1
    int s_hb = wv & 3;             // h 4-block
    int s_wh = wv >> 2;            // w2 half
    int hloc = s_hb * 4 + s_hl;

    // T14: preload ALL chunks' global data (issue-early; consume-late)
    float4 f[4][2][2];
#pragma unroll
    for (int ch = 0; ch < 4; ++ch) {
        int h = ch * 16 + hloc;
#pragma unroll
        for (int st = 0; st < 2; ++st) {
            int w2 = s_wh * 16 + st * 8 + s_p;
            const float* pa = xs + (size_t)h * 4096 + (size_t)w2 * 128 + (c0 + s_cq * 4);
            f[ch][st][0] = *(const float4*)pa;
            f[ch][st][1] = *(const float4*)(pa + 64);
        }
    }

#pragma unroll
    for (int ch = 0; ch < 4; ++ch) {
        int h = ch * 16 + hloc;
        int hb3 = h & 3;
#pragma unroll
        for (int st = 0; st < 2; ++st) {
            int w2 = s_wh * 16 + st * 8 + s_p;
            float a0[4] = {f[ch][st][0].x, f[ch][st][0].y, f[ch][st][0].z, f[ch][st][0].w};
            float a1[4] = {f[ch][st][1].x, f[ch][st][1].y, f[ch][st][1].z, f[ch][st][1].w};
#pragma unroll
            for (int j = 0; j < 4; ++j) {
                int c = s_cq * 4 + j;
                int w2s = w2 ^ ((hb3 ^ ((c & 1) << 1)) << 3);
                P[c * 512 + hloc * 32 + w2s] = bfpack(make_float2(a0[j], a1[j]));
            }
        }
        __syncthreads();
        // compute: 8 g-groups this chunk (4 per team)
#pragma unroll
        for (int gi = 0; gi < 4; ++gi) {
            int g = ch * 8 + gi * 2 + team;
            int h2 = g * 2 + hme;
            int hl2 = h2 & 15;
            int swz = ((h2 & 3) ^ ((cme & 1) << 1)) << 3;
            U48 B[2];
#pragma unroll
            for (int ka = 0; ka < 2; ++ka) {
                int w2a = (ka * 16 + q * 4) ^ swz;
                B[ka].u4 = *(const uint4*)&P[cme * 512 + hl2 * 32 + w2a];
            }
            f32x4 ar = {0.f, 0.f, 0.f, 0.f}, ai = {0.f, 0.f, 0.f, 0.f};
#pragma unroll
            for (int ka = 0; ka < 2; ++ka) {
                ar = __builtin_amdgcn_mfma_f32_16x16x32_bf16(Are[ka].v8, B[ka].v8, ar, 0, 0, 0);
                ai = __builtin_amdgcn_mfma_f32_16x16x32_bf16(Aim[ka].v8, B[ka].v8, ai, 0, 0, 0);
            }
#pragma unroll
            for (int reg = 0; reg < 4; ++reg) {
                int wpp = r * 16 + q * 4 + reg;
                Z[zidx(wpp * 8 + cme, h2)] = bfpack(make_float2(ar[reg], ai[reg]));
            }
        }
        __syncthreads();
    }

    // stage 2: H-DFT (cpx K=128) — unchanged from R5
    U48 Hre[4], Him[4];
#pragma unroll
    for (int ka = 0; ka < 4; ++ka) { Hre[ka] = tw_cpx(wp, q, ka, 0, 1); Him[ka] = tw_cpx(wp, q, ka, 1, 1); }
    size_t ob = (size_t)b * 4194304 + (size_t)t * 64 + (c0 + cme);
#pragma unroll 2
    for (int gi = 0; gi < 16; ++gi) {
        int g = gi * 2 + team;
        int col = g * 16 + m;          // = w*8 + cL
        int w = g * 2 + hme;
        U48 B[4];
#pragma unroll
        for (int ka = 0; ka < 4; ++ka) {
            int h0 = ka * 16 + q * 4;
            int zi = zidx(col, h0);
            B[ka].u2[0] = *(const uint2*)&Z[zi];
            B[ka].u2[1] = *(const uint2*)&Z[zi + 2];
        }
        f32x4 ar = {0.f, 0.f, 0.f, 0.f}, ai = {0.f, 0.f, 0.f, 0.f};
#pragma unroll
        for (int ka = 0; ka < 4; ++ka) {
            ar = __builtin_amdgcn_mfma_f32_16x16x32_bf16(Hre[ka].v8, B[ka].v8, ar, 0, 0, 0);
            ai = __builtin_amdgcn_mfma_f32_16x16x32_bf16(Him[ka].v8, B[ka].v8, ai, 0, 0, 0);
        }
#pragma unroll
        for (int reg = 0; reg < 4; ++reg) {
            int hp = r * 16 + q * 4 + reg;
            X2[ob + (size_t)hp * 65536 + (size_t)w * 1024] = bfpack(make_float2(ar[reg], ai[reg]));
        }
    }
}

// ---------------------------------------------------------------------------
// K3: fused inverse 2D DFT. wg = (b,t,c8). T14 async staging: ALL chunk
// loads issued up-front (16 uint4/thread). Stage 1: H-inv -> Z[(h'*8+c)][w].
// Stage 2: W-inv (real out) -> out fp32.
// ---------------------------------------------------------------------------
__global__ __launch_bounds__(512) void k_inv2d(const unsigned* __restrict__ X3,
                                               float* __restrict__ out) {
    __shared__ unsigned Z[512 * 64];     // 128 KB
    __shared__ unsigned P[8 * 8 * 64];   // 16 KB chunk: [c8][w8][h64]
    int tid = threadIdx.x;
    int lane = tid & 63, r = (tid >> 6) & 3, team = tid >> 8;
    int m = lane & 15, q = lane >> 4;
    int wg = blockIdx.x;
    int bt = wg >> 3;
    int c0 = (wg & 7) * 8;
    const unsigned* xs = X3 + (size_t)bt * 262144;   // (w,h,c) slab
    int wp = r * 16 + m;
    int hme = m >> 3, cme = m & 7;

    // stage-1 twiddles: H-inv (cpx K=128, scale 1/64)
    U48 Hre[4], Him[4];
#pragma unroll
    for (int ka = 0; ka < 4; ++ka) { Hre[ka] = tw_cpx(wp, q, ka, 0, 2); Him[ka] = tw_cpx(wp, q, ka, 1, 2); }

    // T14: preload ALL chunks' global data
    uint4 d[8][2];
#pragma unroll
    for (int cw = 0; cw < 8; ++cw)
#pragma unroll
        for (int it = 0; it < 2; ++it) {
            int u = it * 512 + tid;                 // 0..1023
            int cq = u & 1, h = (u >> 1) & 63, wl = u >> 7;   // wl 0..7
            d[cw][it] = *(const uint4*)(xs + (size_t)(cw * 8 + wl) * 4096
                                           + (size_t)h * 64 + (c0 + cq * 4));
        }

#pragma unroll
    for (int cw = 0; cw < 8; ++cw) {
#pragma unroll
        for (int it = 0; it < 2; ++it) {
            int u = it * 512 + tid;
            int cq = u & 1, h = (u >> 1) & 63, wl = u >> 7;
            unsigned dd[4] = {d[cw][it].x, d[cw][it].y, d[cw][it].z, d[cw][it].w};
#pragma unroll
            for (int j = 0; j < 4; ++j) {
                int c = cq * 4 + j;
                int hs = h ^ ((((wl & 3) ^ ((c & 1) << 1))) << 3);
                P[c * 512 + wl * 64 + hs] = dd[j];
            }
        }
        __syncthreads();
        // compute: 4 g-groups this chunk (2 per team)
#pragma unroll
        for (int gi = 0; gi < 2; ++gi) {
            int g = cw * 4 + gi * 2 + team;
            int w = g * 2 + hme;
            int wl = w & 7;
            int swz = ((wl & 3) ^ ((cme & 1) << 1)) << 3;
            U48 B[4];
#pragma unroll
            for (int ka = 0; ka < 4; ++ka) {
                int ha = (ka * 16 + q * 4) ^ swz;
                B[ka].u4 = *(const uint4*)&P[cme * 512 + wl * 64 + ha];
            }
            f32x4 ar = {0.f, 0.f, 0.f, 0.f}, ai = {0.f, 0.f, 0.f, 0.f};
#pragma unroll
            for (int ka = 0; ka < 4; ++ka) {
                ar = __builtin_amdgcn_mfma_f32_16x16x32_bf16(Hre[ka].v8, B[ka].v8, ar, 0, 0, 0);
                ai = __builtin_amdgcn_mfma_f32_16x16x32_bf16(Him[ka].v8, B[ka].v8, ai, 0, 0, 0);
            }
#pragma unroll
            for (int reg = 0; reg < 4; ++reg) {
                int hp = r * 16 + q * 4 + reg;
                Z[zidx(hp * 8 + cme, w)] = bfpack(make_float2(ar[reg], ai[reg]));
            }
        }
        __syncthreads();
    }

    // stage 2: W-inv (real out, scale 1/64) — unchanged from R5
    U48 Wre[4];
#pragma unroll
    for (int ka = 0; ka < 4; ++ka) Wre[ka] = tw_wi(wp, q, ka);
#pragma unroll 2
    for (int gi = 0; gi < 16; ++gi) {
        int g = gi * 2 + team;
        int col = g * 16 + m;          // = h*8 + cL
        int h = g * 2 + hme;
        U48 B[4];
#pragma unroll
        for (int ka = 0; ka < 4; ++ka) {
            int w0 = ka * 16 + q * 4;
            int zi = zidx(col, w0);
            B[ka].u2[0] = *(const uint2*)&Z[zi];
            B[ka].u2[1] = *(const uint2*)&Z[zi + 2];
        }
        f32x4 ar = {0.f, 0.f, 0.f, 0.f};
#pragma unroll
        for (int ka = 0; ka < 4; ++ka)
            ar = __builtin_amdgcn_mfma_f32_16x16x32_bf16(Wre[ka].v8, B[ka].v8, ar, 0, 0, 0);
        float* dst = out + (size_t)bt * 262144 + (size_t)h * 4096 + (c0 + cme);
#pragma unroll
        for (int reg = 0; reg < 4; ++reg) {
            int wpp = r * 16 + q * 4 + reg;
            dst[(size_t)wpp * 64] = ar[reg];
        }
    }
}

// ---------------------------------------------------------------------------
// K2 (mid): unchanged (verified R4/R5). FFT-16 fwd along T + gates + MFMA
// delta-matmul + scan + FFT-16 inv. X2 (b,h,w,t,c) -> X3 (b,t,w,h,c).
// ---------------------------------------------------------------------------
__global__ __launch_bounds__(256) void k_mid(
    const float* __restrict__ x, const unsigned* __restrict__ X2,
    unsigned* __restrict__ X3,
    const float* __restrict__ Ak, const float* __restrict__ Bk,
    const float* __restrict__ fb, const float* __restrict__ fs,
    const float* __restrict__ ib, const float* __restrict__ isc_,
    const float* __restrict__ dW, const float* __restrict__ db) {
    const float CT[16] = {1.f, 0.9238795f, 0.7071068f, 0.3826834f, 0.f, -0.3826834f,
                          -0.7071068f, -0.9238795f, -1.f, -0.9238795f, -0.7071068f,
                          -0.3826834f, 0.f, 0.3826834f, 0.7071068f, 0.9238795f};
    const float SN[16] = {0.f, 0.3826834f, 0.7071068f, 0.9238795f, 1.f, 0.9238795f,
                          0.7071068f, 0.3826834f, 0.f, -0.3826834f, -0.7071068f,
                          -0.9238795f, -1.f, -0.9238795f, -0.7071068f, -0.3826834f};
    __shared__ float Akl[1728], Bkl[1728];
    __shared__ __align__(16) float xs[4][16 * 68 + 4];

    int tid = threadIdx.x;
    int g = tid >> 6, lane = tid & 63;
    int c = lane;
    int m = lane & 15, q = lane >> 4;
    int site = blockIdx.x * 4 + g;
    int b = site >> 12, hw = site & 4095;
    int h = hw >> 6, w = hw & 63;
    size_t base = (size_t)b * SB_ + (size_t)hw * 64;

    for (int i = tid; i < 1728; i += 256) { Akl[i] = Ak[i]; Bkl[i] = Bk[i]; }

    // delta-W MFMA B-fragments in-register
    U48 Ub[4][2];
#pragma unroll
    for (int nt = 0; nt < 4; ++nt)
#pragma unroll
        for (int ka = 0; ka < 2; ++ka)
#pragma unroll
            for (int p2 = 0; p2 < 4; ++p2) {
                int kb = ka * 32 + q * 8 + 2 * p2;
                int ccol = m + 16 * nt;
                Ub[nt][ka].u[p2] = bfpack(make_float2(dW[kb * 64 + ccol], dW[(kb + 1) * 64 + ccol]));
            }

    float xv[16];
    float2 v[16];
    const unsigned* src2 = X2 + (size_t)site * 1024;
#pragma unroll
    for (int t = 0; t < 16; ++t) {
        xv[t] = x[base + (size_t)t * ST_ + c];
        v[t] = bfunpack(src2[t * 64 + c]);
    }
#pragma unroll
    for (int t = 0; t < 16; ++t) xs[g][t * 68 + c] = xv[t];
    __syncthreads();

    // MFMA delta matmul
    bf16x8 Afrag[2];
#pragma unroll
    for (int ka = 0; ka < 2; ++ka) {
        int d0 = ka * 32 + q * 8;
        const float* p = &xs[g][m * 68 + d0];
        float4 f0 = *(const float4*)p;
        float4 f1 = *(const float4*)(p + 4);
        union { bf16x8 v8; unsigned uu[4]; } U;
        U.uu[0] = bfpack(make_float2(f0.x, f0.y));
        U.uu[1] = bfpack(make_float2(f0.z, f0.w));
        U.uu[2] = bfpack(make_float2(f1.x, f1.y));
        U.uu[3] = bfpack(make_float2(f1.z, f1.w));
        Afrag[ka] = U.v8;
    }
#pragma unroll
    for (int nt = 0; nt < 4; ++nt) {
        int ccol = m + 16 * nt;
        float dbn = db[ccol];
        f32x4 acc = {dbn, dbn, dbn, dbn};
#pragma unroll
        for (int ka = 0; ka < 2; ++ka)
            acc = __builtin_amdgcn_mfma_f32_16x16x32_bf16(Afrag[ka], Ub[nt][ka].v8, acc, 0, 0, 0);
#pragma unroll
        for (int reg = 0; reg < 4; ++reg)
            xs[g][(q * 4 + reg) * 68 + ccol] = acc[reg];
    }

    // A_f/B_f generators from the 27 taps
    float sh, ch; sincosf(TWO_PI * (float)h / 64.0f, &sh, &ch);
    float sw, cw; sincosf(TWO_PI * (float)w / 64.0f, &sw, &cw);
    float2 eh[3] = { make_float2(ch, sh), make_float2(1.f, 0.f), make_float2(ch, -sh) };
    float2 ew[3] = { make_float2(cw, sw), make_float2(1.f, 0.f), make_float2(cw, -sw) };
    float2 GA[3], GB[3];
#pragma unroll
    for (int kt = 0; kt < 3; ++kt) { GA[kt] = make_float2(0.f, 0.f); GB[kt] = make_float2(0.f, 0.f); }
#pragma unroll
    for (int kh = 0; kh < 3; ++kh) {
#pragma unroll
        for (int kw = 0; kw < 3; ++kw) {
            float2 e = cmul(eh[kh], ew[kw]);
#pragma unroll
            for (int kt = 0; kt < 3; ++kt) {
                float ka = Akl[c * 27 + kt * 9 + kh * 3 + kw];
                float kb = Bkl[c * 27 + kt * 9 + kh * 3 + kw];
                GA[kt].x = fmaf(ka, e.x, GA[kt].x);
                GA[kt].y = fmaf(ka, e.y, GA[kt].y);
                GB[kt].x = fmaf(kb, e.x, GB[kt].x);
                GB[kt].y = fmaf(kb, e.y, GB[kt].y);
            }
        }
    }
    float fbc = fb[c], fsc = fs[c], ibc = ib[c], iscv = isc_[c];

    fft16<-1>(v);
    __syncthreads();

    float delta_raw[16];
#pragma unroll
    for (int t = 0; t < 16; ++t) delta_raw[t] = xs[g][t * 68 + c];

    float2 hv = make_float2(0.f, 0.f);
#pragma unroll
    for (int t = 0; t < 16; ++t) {
        float ct = CT[t], st = SN[t];
        float2 Af, Bf;
        Af.x = GA[1].x + ct * (GA[0].x + GA[2].x) - st * (GA[0].y - GA[2].y);
        Af.y = GA[1].y + ct * (GA[0].y + GA[2].y) + st * (GA[0].x - GA[2].x);
        Bf.x = GB[1].x + ct * (GB[0].x + GB[2].x) - st * (GB[0].y - GB[2].y);
        Bf.y = GB[1].y + ct * (GB[0].y + GB[2].y) + st * (GB[0].x - GB[2].x);

        float xc = xv[t];
        float fg  = __builtin_amdgcn_rcpf(1.f + __expf(-(fbc + fsc * xc)));
        float igv = __builtin_amdgcn_rcpf(1.f + __expf(-(ibc + iscv * xc)));
        float dot = delta_raw[t];
        float delta = (dot > 20.f) ? dot : __logf(1.f + __expf(dot));

        float sR = igv * delta;
        float2 bbv;
        bbv.x = sR * (Bf.x * v[t].x - Bf.y * v[t].y);
        bbv.y = sR * (Bf.x * v[t].y + Bf.y * v[t].x);
        float2 av = make_float2(fg * Af.x, fg * Af.y);
        float2 nh;
        nh.x = av.x * hv.x - av.y * hv.y + bbv.x;
        nh.y = av.x * hv.y + av.y * hv.x + bbv.y;
        hv = nh;
        v[t] = hv;
    }

    fft16<1>(v);

    // write X3 (b,t,w,h,c)
    size_t ob = (size_t)b * 4194304 + (size_t)w * 4096 + (size_t)h * 64 + c;
#pragma unroll
    for (int t = 0; t < 16; ++t) {
        float2 o = make_float2(v[t].x * 0.0625f, v[t].y * 0.0625f);
        X3[ob + (size_t)t * 262144] = bfpack(o);
    }
}

extern "C" void kernel_launch(void* const* d_in, const int* in_sizes, int n_in,
                              void* d_out, int out_size, void* d_ws, size_t ws_size,
                              hipStream_t stream) {
    const float* x   = (const float*)d_in[0];
    const float* Ak  = (const float*)d_in[1];
    const float* Bk  = (const float*)d_in[2];
    const float* fb  = (const float*)d_in[3];
    const float* fs  = (const float*)d_in[4];
    const float* ib  = (const float*)d_in[5];
    const float* is_ = (const float*)d_in[6];
    const float* dW  = (const float*)d_in[7];
    const float* db  = (const float*)d_in[8];
    float* out = (float*)d_out;
    unsigned* ws = (unsigned*)d_ws;
    unsigned* X2 = ws + BUF_A;
    unsigned* X3 = ws + BUF_B;

    k_fwd2d<<<Bb * Tt * 8, 512, 0, stream>>>(x, X2);
    k_mid<<<(Bb * Hh * Ww) / 4, 256, 0, stream>>>(x, X2, X3, Ak, Bk, fb, fs, ib, is_, dW, db);
    k_inv2d<<<Bb * Tt * 8, 512, 0, stream>>>(X3, out);
}

// Round 8
// 189.610 us; speedup vs baseline: 1.3299x; 1.0613x over previous
//
#include <hip/hip_runtime.h>
#include <math.h>

// Problem dims
#define Bb 2
#define Tt 16
#define Hh 64
#define Ww 64
#define Cc 64
#define ST_ (Hh*Ww*Cc)    // 262144
#define SB_ (Tt*Hh*Ww*Cc) // 4194304

#define TWO_PI 6.2831853071795864769f

typedef __attribute__((ext_vector_type(8))) short bf16x8;
typedef __attribute__((ext_vector_type(4))) float f32x4;

// workspace u32-offsets: two ping-pong X buffers
#define BUF_A    0u
#define BUF_B    8388608u

__device__ __forceinline__ float2 cmul(float2 a, float2 b) {
    return make_float2(fmaf(a.x, b.x, -a.y * b.y), fmaf(a.x, b.y, a.y * b.x));
}
__device__ __forceinline__ float2 cadd(float2 a, float2 b) { return make_float2(a.x + b.x, a.y + b.y); }
__device__ __forceinline__ float2 csub(float2 a, float2 b) { return make_float2(a.x - b.x, a.y - b.y); }

// bf16 pair pack/unpack (x -> low 16, y -> high 16). RNE; range = fp32.
__device__ __forceinline__ unsigned bfpack(float2 f) {
    unsigned r = __float_as_uint(f.x);
    unsigned i = __float_as_uint(f.y);
    r = (r + 0x7fffu + ((r >> 16) & 1u)) >> 16;
    i = (i + 0x7fffu + ((i >> 16) & 1u)) >> 16;
    return r | (i << 16);
}
__device__ __forceinline__ float2 bfunpack(unsigned u) {
    return make_float2(__uint_as_float(u << 16), __uint_as_float(u & 0xffff0000u));
}

union U48 { uint4 u4; uint2 u2[2]; unsigned u[4]; bf16x8 v8; };

// ---------------------------------------------------------------------------
// In-register twiddle fragment builders (verified R4..R6).
// wp = r*16+m (A-row), k0 = ka*32 + q*8 + 2p.
// ---------------------------------------------------------------------------
__device__ __forceinline__ U48 tw_wf(int wp, int q, int ka, int reim) {
    U48 o;
#pragma unroll
    for (int p = 0; p < 4; ++p) {
        int k0 = ka * 32 + q * 8 + 2 * p;
        float v[2];
#pragma unroll
        for (int dk = 0; dk < 2; ++dk) {
            int k = k0 + dk;
            int a = (wp * k) & 63;
            float sn, cs; sincosf(TWO_PI * (float)a * (1.0f / 64.0f), &sn, &cs);
            v[dk] = reim ? -sn : cs;
        }
        o.u[p] = bfpack(make_float2(v[0], v[1]));
    }
    return o;
}

// tbl: 1 = fwd H (cpx K=128), 2 = inv H (cpx K=128, scale 1/64)
__device__ __forceinline__ U48 tw_cpx(int wp, int q, int ka, int reim, int tbl) {
    U48 o;
#pragma unroll
    for (int p = 0; p < 4; ++p) {
        int k0 = ka * 32 + q * 8 + 2 * p;
        float v[2];
#pragma unroll
        for (int dk = 0; dk < 2; ++dk) {
            int k = k0 + dk;
            int h = k >> 1;
            int a = (wp * h) & 63;
            float sn, cs; sincosf(TWO_PI * (float)a * (1.0f / 64.0f), &sn, &cs);
            bool even = (k & 1) == 0;
            float vv;
            if (tbl == 1) vv = reim ? (even ? -sn : cs) : (even ? cs : sn);
            else          vv = (reim ? (even ? sn : cs) : (even ? cs : -sn)) * (1.0f / 64.0f);
            v[dk] = vv;
        }
        o.u[p] = bfpack(make_float2(v[0], v[1]));
    }
    return o;
}

// inv W, real output, scale 1/64
__device__ __forceinline__ U48 tw_wi(int wp, int q, int ka) {
    U48 o;
#pragma unroll
    for (int p = 0; p < 4; ++p) {
        int k0 = ka * 32 + q * 8 + 2 * p;
        float v[2];
#pragma unroll
        for (int dk = 0; dk < 2; ++dk) {
            int k = k0 + dk;
            int h = k >> 1;
            int a = (wp * h) & 63;
            float sn, cs; sincosf(TWO_PI * (float)a * (1.0f / 64.0f), &sn, &cs);
            bool even = (k & 1) == 0;
            v[dk] = (even ? cs : -sn) * (1.0f / 64.0f);
        }
        o.u[p] = bfpack(make_float2(v[0], v[1]));
    }
    return o;
}

// LDS index for the 256-col x 64-pt Z buffer (64 KB): verified R6.
__device__ __forceinline__ int zidx(int col, int h) {
    return (col << 6) + (h ^ (((col >> 1) & 7) << 3));
}

template <int S>
__device__ __forceinline__ void fft4(float2& a, float2& b, float2& c, float2& d) {
    float2 t0 = cadd(a, c), t1 = csub(a, c);
    float2 t2 = cadd(b, d), t3 = csub(b, d);
    a = cadd(t0, t2);
    c = csub(t0, t2);
    b = make_float2(t1.x - (float)S * t3.y, t1.y + (float)S * t3.x);
    d = make_float2(t1.x + (float)S * t3.y, t1.y - (float)S * t3.x);
}

// 16-pt FFT in registers, natural order in/out, radix 4x4.
template <int S>
__device__ __forceinline__ void fft16(float2 v[16]) {
    const float CS[10] = {1.f, 0.92387953f, 0.70710678f, 0.38268343f, 0.f,
                          -0.38268343f, -0.70710678f, -0.92387953f, -1.f, -0.92387953f};
    const float SN[10] = {0.f, 0.38268343f, 0.70710678f, 0.92387953f, 1.f,
                          0.92387953f, 0.70710678f, 0.38268343f, 0.f, -0.38268343f};
    float2 A[4][4];
#pragma unroll
    for (int j = 0; j < 4; ++j) {
        A[j][0] = v[j]; A[j][1] = v[4 + j]; A[j][2] = v[8 + j]; A[j][3] = v[12 + j];
        fft4<S>(A[j][0], A[j][1], A[j][2], A[j][3]);
#pragma unroll
        for (int k0 = 0; k0 < 4; ++k0) {
            int m = j * k0;
            float2 tw = make_float2(CS[m], (float)S * SN[m]);
            A[j][k0] = cmul(A[j][k0], tw);
        }
    }
#pragma unroll
    for (int k0 = 0; k0 < 4; ++k0) {
        fft4<S>(A[0][k0], A[1][k0], A[2][k0], A[3][k0]);
        v[k0] = A[0][k0]; v[k0 + 4] = A[1][k0]; v[k0 + 8] = A[2][k0]; v[k0 + 12] = A[3][k0];
    }
}

// XCD-grouping remap (grid 512, 8 XCDs, blockIdx k -> XCD k&7 round-robin):
// all 16 c4-wgs of one (b,t) slab land on ONE XCD -> their 4-way line
// sharing is served by that XCD's L2 instead of 4x HBM fetches.
__device__ __forceinline__ void xcd_decode(int k, int& bt, int& c0) {
    int xcd = k & 7, s = k >> 3;         // s in [0,64)
    bt = xcd * 4 + (s >> 4);             // 4 slabs per XCD
    c0 = (s & 15) * 4;                   // 16 c4 slices per slab
}

// ---------------------------------------------------------------------------
// K1: fused forward 2D DFT-64x64. wg = (b,t,c4): grid 512, 512 thr = 8 waves
// (2 teams x 4 row-quarters). LDS 72 KB -> 2 wg/CU. All chunk data preloaded
// to registers (8 float4) before the chunk loop. Stage 1: W-DFT (real K=64)
// -> Z[(w'*4+c)][h]. Stage 2: H-DFT (cpx K=128) from Z -> X2 (b,h,w,t,c).
// ---------------------------------------------------------------------------
__global__ __launch_bounds__(512, 4) void k_fwd2d(const float* __restrict__ x,
                                                  unsigned* __restrict__ X2) {
    __shared__ unsigned Z[256 * 64];     // 64 KB
    __shared__ unsigned P[4 * 16 * 32];  // 8 KB chunk: [c4][h16][w2]
    int tid = threadIdx.x;
    int lane = tid & 63, r = (tid >> 6) & 3, team = tid >> 8;
    int m = lane & 15, q = lane >> 4;
    int bt, c0;
    xcd_decode(blockIdx.x, bt, c0);
    int b = bt >> 4, t = bt & 15;
    const float* xs = x + (size_t)bt * 262144;   // (h,w,c) slab
    int wp = r * 16 + m;
    int hme = m >> 2, cme = m & 3;

    // stage-1 twiddles
    U48 Are[2], Aim[2];
#pragma unroll
    for (int ka = 0; ka < 2; ++ka) { Are[ka] = tw_wf(wp, q, ka, 0); Aim[ka] = tw_wf(wp, q, ka, 1); }

    // preload ALL chunks: one pair-site (h, w2) per thread per chunk
    int s_h = tid >> 5;            // hloc 0..15
    int s_w2 = tid & 31;           // w2 0..31
    float4 f[4][2];
#pragma unroll
    for (int ch = 0; ch < 4; ++ch) {
        const float* pa = xs + (size_t)(ch * 16 + s_h) * 4096 + (size_t)s_w2 * 128 + c0;
        f[ch][0] = *(const float4*)pa;
        f[ch][1] = *(const float4*)(pa + 64);
    }

    for (int ch = 0; ch < 4; ++ch) {
        int h = ch * 16 + s_h;
        float a0[4] = {f[ch][0].x, f[ch][0].y, f[ch][0].z, f[ch][0].w};
        float a1[4] = {f[ch][1].x, f[ch][1].y, f[ch][1].z, f[ch][1].w};
#pragma unroll
        for (int j = 0; j < 4; ++j) {
            int w2s = s_w2 ^ ((((h & 3) ^ ((j & 1) << 1))) << 3);
            P[j * 512 + s_h * 32 + w2s] = bfpack(make_float2(a0[j], a1[j]));
        }
        __syncthreads();
        // compute: 4 g-groups this chunk (2 per team); g covers 4 h x 4 c
#pragma unroll
        for (int gi = 0; gi < 2; ++gi) {
            int g = ch * 4 + gi * 2 + team;
            int h2 = g * 4 + hme;
            int hl2 = h2 & 15;
            int swz = ((h2 & 3) ^ ((cme & 1) << 1)) << 3;
            U48 B[2];
#pragma unroll
            for (int ka = 0; ka < 2; ++ka) {
                int w2a = (ka * 16 + q * 4) ^ swz;
                B[ka].u4 = *(const uint4*)&P[cme * 512 + hl2 * 32 + w2a];
            }
            f32x4 ar = {0.f, 0.f, 0.f, 0.f}, ai = {0.f, 0.f, 0.f, 0.f};
#pragma unroll
            for (int ka = 0; ka < 2; ++ka) {
                ar = __builtin_amdgcn_mfma_f32_16x16x32_bf16(Are[ka].v8, B[ka].v8, ar, 0, 0, 0);
                ai = __builtin_amdgcn_mfma_f32_16x16x32_bf16(Aim[ka].v8, B[ka].v8, ai, 0, 0, 0);
            }
#pragma unroll
            for (int reg = 0; reg < 4; ++reg) {
                int wpp = r * 16 + q * 4 + reg;
                Z[zidx(wpp * 4 + cme, h2)] = bfpack(make_float2(ar[reg], ai[reg]));
            }
        }
        __syncthreads();
    }

    // stage 2: H-DFT (cpx K=128) from Z -> X2
    U48 Hre[4], Him[4];
#pragma unroll
    for (int ka = 0; ka < 4; ++ka) { Hre[ka] = tw_cpx(wp, q, ka, 0, 1); Him[ka] = tw_cpx(wp, q, ka, 1, 1); }
    size_t ob = (size_t)b * 4194304 + (size_t)t * 64 + (c0 + cme);
#pragma unroll 2
    for (int gi = 0; gi < 8; ++gi) {
        int g = gi * 2 + team;
        int col = g * 16 + m;          // = w*4 + cL
        int w = g * 4 + hme;
        U48 B[4];
#pragma unroll
        for (int ka = 0; ka < 4; ++ka) {
            int h0 = ka * 16 + q * 4;
            int zi = zidx(col, h0);
            B[ka].u2[0] = *(const uint2*)&Z[zi];
            B[ka].u2[1] = *(const uint2*)&Z[zi + 2];
        }
        f32x4 ar = {0.f, 0.f, 0.f, 0.f}, ai = {0.f, 0.f, 0.f, 0.f};
#pragma unroll
        for (int ka = 0; ka < 4; ++ka) {
            ar = __builtin_amdgcn_mfma_f32_16x16x32_bf16(Hre[ka].v8, B[ka].v8, ar, 0, 0, 0);
            ai = __builtin_amdgcn_mfma_f32_16x16x32_bf16(Him[ka].v8, B[ka].v8, ai, 0, 0, 0);
        }
#pragma unroll
        for (int reg = 0; reg < 4; ++reg) {
            int hp = r * 16 + q * 4 + reg;
            X2[ob + (size_t)hp * 65536 + (size_t)w * 1024] = bfpack(make_float2(ar[reg], ai[reg]));
        }
    }
}

// ---------------------------------------------------------------------------
// K3: fused inverse 2D DFT. wg = (b,t,c4): grid 512. LDS 72 KB -> 2 wg/CU.
// All chunk data preloaded (8 uint4). Stage 1: H-inv (cpx K=128, 1/64) from
// P -> Z[(h'*4+c)][w]. Stage 2: W-inv (real out, 1/64) -> out fp32.
// ---------------------------------------------------------------------------
__global__ __launch_bounds__(512, 4) void k_inv2d(const unsigned* __restrict__ X3,
                                                  float* __restrict__ out) {
    __shared__ unsigned Z[256 * 64];     // 64 KB
    __shared__ unsigned P[4 * 8 * 64];   // 8 KB chunk: [c4][w8][h64]
    int tid = threadIdx.x;
    int lane = tid & 63, r = (tid >> 6) & 3, team = tid >> 8;
    int m = lane & 15, q = lane >> 4;
    int bt, c0;
    xcd_decode(blockIdx.x, bt, c0);
    const unsigned* xs = X3 + (size_t)bt * 262144;   // (w,h,c) slab
    int wp = r * 16 + m;
    int hme = m >> 2, cme = m & 3;

    // stage-1 twiddles: H-inv
    U48 Hre[4], Him[4];
#pragma unroll
    for (int ka = 0; ka < 4; ++ka) { Hre[ka] = tw_cpx(wp, q, ka, 0, 2); Him[ka] = tw_cpx(wp, q, ka, 1, 2); }

    // preload ALL chunks: one (w,h) site per thread per chunk
    int s_wl = tid >> 6;           // 0..7
    int s_hh = tid & 63;           // 0..63
    uint4 d[8];
#pragma unroll
    for (int cw = 0; cw < 8; ++cw)
        d[cw] = *(const uint4*)(xs + (size_t)(cw * 8 + s_wl) * 4096 + (size_t)s_hh * 64 + c0);

    for (int cw = 0; cw < 8; ++cw) {
        unsigned dd[4] = {d[cw].x, d[cw].y, d[cw].z, d[cw].w};
#pragma unroll
        for (int j = 0; j < 4; ++j) {
            int hs = s_hh ^ ((((s_wl & 3) ^ ((j & 1) << 1))) << 3);
            P[j * 512 + s_wl * 64 + hs] = dd[j];
        }
        __syncthreads();
        // compute: 2 g-groups this chunk (1 per team); g covers 4 w x 4 c
        {
            int g = cw * 2 + team;
            int w = g * 4 + hme;
            int wl = w & 7;
            int swz = ((wl & 3) ^ ((cme & 1) << 1)) << 3;
            U48 B[4];
#pragma unroll
            for (int ka = 0; ka < 4; ++ka) {
                int ha = (ka * 16 + q * 4) ^ swz;
                B[ka].u4 = *(const uint4*)&P[cme * 512 + wl * 64 + ha];
            }
            f32x4 ar = {0.f, 0.f, 0.f, 0.f}, ai = {0.f, 0.f, 0.f, 0.f};
#pragma unroll
            for (int ka = 0; ka < 4; ++ka) {
                ar = __builtin_amdgcn_mfma_f32_16x16x32_bf16(Hre[ka].v8, B[ka].v8, ar, 0, 0, 0);
                ai = __builtin_amdgcn_mfma_f32_16x16x32_bf16(Him[ka].v8, B[ka].v8, ai, 0, 0, 0);
            }
#pragma unroll
            for (int reg = 0; reg < 4; ++reg) {
                int hp = r * 16 + q * 4 + reg;
                Z[zidx(hp * 4 + cme, w)] = bfpack(make_float2(ar[reg], ai[reg]));
            }
        }
        __syncthreads();
    }

    // stage 2: W-inv (real out)
    U48 Wre[4];
#pragma unroll
    for (int ka = 0; ka < 4; ++ka) Wre[ka] = tw_wi(wp, q, ka);
#pragma unroll 2
    for (int gi = 0; gi < 8; ++gi) {
        int g = gi * 2 + team;
        int col = g * 16 + m;          // = h*4 + cL
        int h = g * 4 + hme;
        U48 B[4];
#pragma unroll
        for (int ka = 0; ka < 4; ++ka) {
            int w0 = ka * 16 + q * 4;
            int zi = zidx(col, w0);
            B[ka].u2[0] = *(const uint2*)&Z[zi];
            B[ka].u2[1] = *(const uint2*)&Z[zi + 2];
        }
        f32x4 ar = {0.f, 0.f, 0.f, 0.f};
#pragma unroll
        for (int ka = 0; ka < 4; ++ka)
            ar = __builtin_amdgcn_mfma_f32_16x16x32_bf16(Wre[ka].v8, B[ka].v8, ar, 0, 0, 0);
        float* dst = out + (size_t)bt * 262144 + (size_t)h * 4096 + (c0 + cme);
#pragma unroll
        for (int reg = 0; reg < 4; ++reg) {
            int wpp = r * 16 + q * 4 + reg;
            dst[(size_t)wpp * 64] = ar[reg];
        }
    }
}

// ---------------------------------------------------------------------------
// K2 (mid): unchanged (verified R4..R6). FFT-16 fwd along T + gates + MFMA
// delta-matmul + scan + FFT-16 inv. X2 (b,h,w,t,c) -> X3 (b,t,w,h,c).
// ---------------------------------------------------------------------------
__global__ __launch_bounds__(256) void k_mid(
    const float* __restrict__ x, const unsigned* __restrict__ X2,
    unsigned* __restrict__ X3,
    const float* __restrict__ Ak, const float* __restrict__ Bk,
    const float* __restrict__ fb, const float* __restrict__ fs,
    const float* __restrict__ ib, const float* __restrict__ isc_,
    const float* __restrict__ dW, const float* __restrict__ db) {
    const float CT[16] = {1.f, 0.9238795f, 0.7071068f, 0.3826834f, 0.f, -0.3826834f,
                          -0.7071068f, -0.9238795f, -1.f, -0.9238795f, -0.7071068f,
                          -0.3826834f, 0.f, 0.3826834f, 0.7071068f, 0.9238795f};
    const float SN[16] = {0.f, 0.3826834f, 0.7071068f, 0.9238795f, 1.f, 0.9238795f,
                          0.7071068f, 0.3826834f, 0.f, -0.3826834f, -0.7071068f,
                          -0.9238795f, -1.f, -0.9238795f, -0.7071068f, -0.3826834f};
    __shared__ float Akl[1728], Bkl[1728];
    __shared__ __align__(16) float xs[4][16 * 68 + 4];

    int tid = threadIdx.x;
    int g = tid >> 6, lane = tid & 63;
    int c = lane;
    int m = lane & 15, q = lane >> 4;
    int site = blockIdx.x * 4 + g;
    int b = site >> 12, hw = site & 4095;
    int h = hw >> 6, w = hw & 63;
    size_t base = (size_t)b * SB_ + (size_t)hw * 64;

    for (int i = tid; i < 1728; i += 256) { Akl[i] = Ak[i]; Bkl[i] = Bk[i]; }

    // delta-W MFMA B-fragments in-register
    U48 Ub[4][2];
#pragma unroll
    for (int nt = 0; nt < 4; ++nt)
#pragma unroll
        for (int ka = 0; ka < 2; ++ka)
#pragma unroll
            for (int p2 = 0; p2 < 4; ++p2) {
                int kb = ka * 32 + q * 8 + 2 * p2;
                int ccol = m + 16 * nt;
                Ub[nt][ka].u[p2] = bfpack(make_float2(dW[kb * 64 + ccol], dW[(kb + 1) * 64 + ccol]));
            }

    float xv[16];
    float2 v[16];
    const unsigned* src2 = X2 + (size_t)site * 1024;
#pragma unroll
    for (int t = 0; t < 16; ++t) {
        xv[t] = x[base + (size_t)t * ST_ + c];
        v[t] = bfunpack(src2[t * 64 + c]);
    }
#pragma unroll
    for (int t = 0; t < 16; ++t) xs[g][t * 68 + c] = xv[t];
    __syncthreads();

    // MFMA delta matmul
    bf16x8 Afrag[2];
#pragma unroll
    for (int ka = 0; ka < 2; ++ka) {
        int d0 = ka * 32 + q * 8;
        const float* p = &xs[g][m * 68 + d0];
        float4 f0 = *(const float4*)p;
        float4 f1 = *(const float4*)(p + 4);
        union { bf16x8 v8; unsigned uu[4]; } U;
        U.uu[0] = bfpack(make_float2(f0.x, f0.y));
        U.uu[1] = bfpack(make_float2(f0.z, f0.w));
        U.uu[2] = bfpack(make_float2(f1.x, f1.y));
        U.uu[3] = bfpack(make_float2(f1.z, f1.w));
        Afrag[ka] = U.v8;
    }
#pragma unroll
    for (int nt = 0; nt < 4; ++nt) {
        int ccol = m + 16 * nt;
        float dbn = db[ccol];
        f32x4 acc = {dbn, dbn, dbn, dbn};
#pragma unroll
        for (int ka = 0; ka < 2; ++ka)
            acc = __builtin_amdgcn_mfma_f32_16x16x32_bf16(Afrag[ka], Ub[nt][ka].v8, acc, 0, 0, 0);
#pragma unroll
        for (int reg = 0; reg < 4; ++reg)
            xs[g][(q * 4 + reg) * 68 + ccol] = acc[reg];
    }

    // A_f/B_f generators from the 27 taps
    float sh, ch; sincosf(TWO_PI * (float)h / 64.0f, &sh, &ch);
    float sw, cw; sincosf(TWO_PI * (float)w / 64.0f, &sw, &cw);
    float2 eh[3] = { make_float2(ch, sh), make_float2(1.f, 0.f), make_float2(ch, -sh) };
    float2 ew[3] = { make_float2(cw, sw), make_float2(1.f, 0.f), make_float2(cw, -sw) };
    float2 GA[3], GB[3];
#pragma unroll
    for (int kt = 0; kt < 3; ++kt) { GA[kt] = make_float2(0.f, 0.f); GB[kt] = make_float2(0.f, 0.f); }
#pragma unroll
    for (int kh = 0; kh < 3; ++kh) {
#pragma unroll
        for (int kw = 0; kw < 3; ++kw) {
            float2 e = cmul(eh[kh], ew[kw]);
#pragma unroll
            for (int kt = 0; kt < 3; ++kt) {
                float ka = Akl[c * 27 + kt * 9 + kh * 3 + kw];
                float kb = Bkl[c * 27 + kt * 9 + kh * 3 + kw];
                GA[kt].x = fmaf(ka, e.x, GA[kt].x);
                GA[kt].y = fmaf(ka, e.y, GA[kt].y);
                GB[kt].x = fmaf(kb, e.x, GB[kt].x);
                GB[kt].y = fmaf(kb, e.y, GB[kt].y);
            }
        }
    }
    float fbc = fb[c], fsc = fs[c], ibc = ib[c], iscv = isc_[c];

    fft16<-1>(v);
    __syncthreads();

    float delta_raw[16];
#pragma unroll
    for (int t = 0; t < 16; ++t) delta_raw[t] = xs[g][t * 68 + c];

    float2 hv = make_float2(0.f, 0.f);
#pragma unroll
    for (int t = 0; t < 16; ++t) {
        float ct = CT[t], st = SN[t];
        float2 Af, Bf;
        Af.x = GA[1].x + ct * (GA[0].x + GA[2].x) - st * (GA[0].y - GA[2].y);
        Af.y = GA[1].y + ct * (GA[0].y + GA[2].y) + st * (GA[0].x - GA[2].x);
        Bf.x = GB[1].x + ct * (GB[0].x + GB[2].x) - st * (GB[0].y - GB[2].y);
        Bf.y = GB[1].y + ct * (GB[0].y + GB[2].y) + st * (GB[0].x - GB[2].x);

        float xc = xv[t];
        float fg  = __builtin_amdgcn_rcpf(1.f + __expf(-(fbc + fsc * xc)));
        float igv = __builtin_amdgcn_rcpf(1.f + __expf(-(ibc + iscv * xc)));
        float dot = delta_raw[t];
        float delta = (dot > 20.f) ? dot : __logf(1.f + __expf(dot));

        float sR = igv * delta;
        float2 bbv;
        bbv.x = sR * (Bf.x * v[t].x - Bf.y * v[t].y);
        bbv.y = sR * (Bf.x * v[t].y + Bf.y * v[t].x);
        float2 av = make_float2(fg * Af.x, fg * Af.y);
        float2 nh;
        nh.x = av.x * hv.x - av.y * hv.y + bbv.x;
        nh.y = av.x * hv.y + av.y * hv.x + bbv.y;
        hv = nh;
        v[t] = hv;
    }

    fft16<1>(v);

    // write X3 (b,t,w,h,c)
    size_t ob = (size_t)b * 4194304 + (size_t)w * 4096 + (size_t)h * 64 + c;
#pragma unroll
    for (int t = 0; t < 16; ++t) {
        float2 o = make_float2(v[t].x * 0.0625f, v[t].y * 0.0625f);
        X3[ob + (size_t)t * 262144] = bfpack(o);
    }
}

extern "C" void kernel_launch(void* const* d_in, const int* in_sizes, int n_in,
                              void* d_out, int out_size, void* d_ws, size_t ws_size,
                              hipStream_t stream) {
    const float* x   = (const float*)d_in[0];
    const float* Ak  = (const float*)d_in[1];
    const float* Bk  = (const float*)d_in[2];
    const float* fb  = (const float*)d_in[3];
    const float* fs  = (const float*)d_in[4];
    const float* ib  = (const float*)d_in[5];
    const float* is_ = (const float*)d_in[6];
    const float* dW  = (const float*)d_in[7];
    const float* db  = (const float*)d_in[8];
    float* out = (float*)d_out;
    unsigned* ws = (unsigned*)d_ws;
    unsigned* X2 = ws + BUF_A;
    unsigned* X3 = ws + BUF_B;

    k_fwd2d<<<Bb * Tt * 16, 512, 0, stream>>>(x, X2);
    k_mid<<<(Bb * Hh * Ww) / 4, 256, 0, stream>>>(x, X2, X3, Ak, Bk, fb, fs, ib, is_, dW, db);
    k_inv2d<<<Bb * Tt * 16, 512, 0, stream>>>(X3, out);
}

// Round 9
// 172.586 us; speedup vs baseline: 1.4611x; 1.0986x over previous
//
#include <hip/hip_runtime.h>
#include <math.h>

// Problem dims
#define Bb 2
#define Tt 16
#define Hh 64
#define Ww 64
#define Cc 64
#define ST_ (Hh*Ww*Cc)    // 262144
#define SB_ (Tt*Hh*Ww*Cc) // 4194304

#define TWO_PI 6.2831853071795864769f

typedef __attribute__((ext_vector_type(8))) short bf16x8;
typedef __attribute__((ext_vector_type(4))) float f32x4;

// workspace u32-offsets: two ping-pong X buffers + twiddle tables
#define BUF_A    0u
#define BUF_B    8388608u
#define OFF_PRE  16777216u
#define OFF_TWF  16779264u   // fwd W (real, K=64, re+im)      4096 u32
#define OFF_THF  16783360u   // fwd H (cpx K=128, re+im)       8192 u32
#define OFF_THI  16791552u   // inv H (cpx K=128, re+im, /64)  8192 u32
#define OFF_TWI  16799744u   // inv W (cpx K=128, re only,/64) 4096 u32

__device__ __forceinline__ float2 cmul(float2 a, float2 b) {
    return make_float2(fmaf(a.x, b.x, -a.y * b.y), fmaf(a.x, b.y, a.y * b.x));
}
__device__ __forceinline__ float2 cadd(float2 a, float2 b) { return make_float2(a.x + b.x, a.y + b.y); }
__device__ __forceinline__ float2 csub(float2 a, float2 b) { return make_float2(a.x - b.x, a.y - b.y); }

// bf16 pair pack/unpack (x -> low 16, y -> high 16). RNE; range = fp32.
__device__ __forceinline__ unsigned bfpack(float2 f) {
    unsigned r = __float_as_uint(f.x);
    unsigned i = __float_as_uint(f.y);
    r = (r + 0x7fffu + ((r >> 16) & 1u)) >> 16;
    i = (i + 0x7fffu + ((i >> 16) & 1u)) >> 16;
    return r | (i << 16);
}
__device__ __forceinline__ float2 bfunpack(unsigned u) {
    return make_float2(__uint_as_float(u << 16), __uint_as_float(u & 0xffff0000u));
}

union U48 { uint4 u4; uint2 u2[2]; unsigned u[4]; bf16x8 v8; };

// ---------------------------------------------------------------------------
// Setup: delta-W fragments (unused, kept verbatim) + 4 twiddle tables.
// VERIFIED in R0-R3; idx decode maps to uint4 loads
// T_wf[((reim*4+r)*2+ka)*64+lane], T_{hf,hi}[((reim*4+r)*4+ka)*64+lane],
// T_wi[(r*4+ka)*64+lane].
// ---------------------------------------------------------------------------
__global__ __launch_bounds__(256) void k_setup(const float* __restrict__ dW,
                                               unsigned* __restrict__ ws) {
    int j = blockIdx.x * 256 + threadIdx.x;   // 0..26623
    if (j < 2048) {
        int p2 = j & 3, lane = (j >> 2) & 63, ka = (j >> 8) & 1, nt = j >> 9;
        int kb = ka * 32 + (lane >> 4) * 8 + 2 * p2;
        int ccol = (lane & 15) + 16 * nt;
        ws[OFF_PRE + j] = bfpack(make_float2(dW[kb * 64 + ccol], dW[(kb + 1) * 64 + ccol]));
        return;
    }
    int idx, table;
    if (j < 6144)       { idx = j - 2048;  table = 0; }   // T_wf
    else if (j < 14336) { idx = j - 6144;  table = 1; }   // T_hf
    else if (j < 22528) { idx = j - 14336; table = 2; }   // T_hi
    else                { idx = j - 22528; table = 3; }   // T_wi
    int p = idx & 3;
    int lane = (idx >> 2) & 63;
    int m = lane & 15, q = lane >> 4;
    int ka, r, reim;
    if (table == 0)      { ka = (idx >> 8) & 1; r = (idx >> 9) & 3;  reim = (idx >> 11) & 1; }
    else if (table == 3) { ka = (idx >> 8) & 3; r = (idx >> 10) & 3; reim = 0; }
    else                 { ka = (idx >> 8) & 3; r = (idx >> 10) & 3; reim = (idx >> 12) & 1; }
    int wp = r * 16 + m;
    int k0 = ka * 32 + q * 8 + 2 * p;
    float val[2];
#pragma unroll
    for (int dk = 0; dk < 2; ++dk) {
        int k = k0 + dk;
        float v;
        if (table == 0) {
            int a = (wp * k) & 63;
            float sn, cs; sincosf(TWO_PI * (float)a * (1.0f / 64.0f), &sn, &cs);
            v = (reim == 0) ? cs : -sn;
        } else {
            int h = k >> 1;
            int a = (wp * h) & 63;
            float sn, cs; sincosf(TWO_PI * (float)a * (1.0f / 64.0f), &sn, &cs);
            bool even = (k & 1) == 0;
            if (table == 1) {
                v = (reim == 0) ? (even ? cs : sn) : (even ? -sn : cs);
            } else if (table == 2) {
                v = (reim == 0) ? (even ? cs : -sn) : (even ? sn : cs);
                v *= (1.0f / 64.0f);
            } else {
                v = (even ? cs : -sn) * (1.0f / 64.0f);
            }
        }
        val[dk] = v;
    }
    unsigned base = (table == 0) ? OFF_TWF : (table == 1) ? OFF_THF
                  : (table == 2) ? OFF_THI : OFF_TWI;
    ws[base + idx] = bfpack(make_float2(val[0], val[1]));
}

// LDS index for the 256-col x 64-pt Z buffer (64 KB): verified R6/R8.
__device__ __forceinline__ int zidx(int col, int h) {
    return (col << 6) + (h ^ (((col >> 1) & 7) << 3));
}

template <int S>
__device__ __forceinline__ void fft4(float2& a, float2& b, float2& c, float2& d) {
    float2 t0 = cadd(a, c), t1 = csub(a, c);
    float2 t2 = cadd(b, d), t3 = csub(b, d);
    a = cadd(t0, t2);
    c = csub(t0, t2);
    b = make_float2(t1.x - (float)S * t3.y, t1.y + (float)S * t3.x);
    d = make_float2(t1.x + (float)S * t3.y, t1.y - (float)S * t3.x);
}

// 16-pt FFT in registers, natural order in/out, radix 4x4.
template <int S>
__device__ __forceinline__ void fft16(float2 v[16]) {
    const float CS[10] = {1.f, 0.92387953f, 0.70710678f, 0.38268343f, 0.f,
                          -0.38268343f, -0.70710678f, -0.92387953f, -1.f, -0.92387953f};
    const float SN[10] = {0.f, 0.38268343f, 0.70710678f, 0.92387953f, 1.f,
                          0.92387953f, 0.70710678f, 0.38268343f, 0.f, -0.38268343f};
    float2 A[4][4];
#pragma unroll
    for (int j = 0; j < 4; ++j) {
        A[j][0] = v[j]; A[j][1] = v[4 + j]; A[j][2] = v[8 + j]; A[j][3] = v[12 + j];
        fft4<S>(A[j][0], A[j][1], A[j][2], A[j][3]);
#pragma unroll
        for (int k0 = 0; k0 < 4; ++k0) {
            int m = j * k0;
            float2 tw = make_float2(CS[m], (float)S * SN[m]);
            A[j][k0] = cmul(A[j][k0], tw);
        }
    }
#pragma unroll
    for (int k0 = 0; k0 < 4; ++k0) {
        fft4<S>(A[0][k0], A[1][k0], A[2][k0], A[3][k0]);
        v[k0] = A[0][k0]; v[k0 + 4] = A[1][k0]; v[k0 + 8] = A[2][k0]; v[k0 + 12] = A[3][k0];
    }
}

// XCD-grouping remap (grid 512, 8 XCDs, blockIdx k -> XCD k&7 round-robin):
// all 16 c4-wgs of one (b,t) slab land on ONE XCD -> 4-way line sharing is
// served by that XCD's L2. Verified R8: FETCH 131 -> 16.7 MB.
__device__ __forceinline__ void xcd_decode(int k, int& bt, int& c0) {
    int xcd = k & 7, s = k >> 3;         // s in [0,64)
    bt = xcd * 4 + (s >> 4);             // 4 slabs per XCD
    c0 = (s & 15) * 4;                   // 16 c4 slices per slab
}

// ---------------------------------------------------------------------------
// K1: fused forward 2D DFT-64x64. wg = (b,t,c4): grid 512, 512 thr = 8 waves.
// Twiddles from precomputed tables (12 uint4 loads, issued at entry).
// Stage 1: W-DFT (real K=64) -> Z[(w'*4+c)][h]. Stage 2: H-DFT -> X2.
// ---------------------------------------------------------------------------
__global__ __launch_bounds__(512, 4) void k_fwd2d(const float* __restrict__ x,
                                                  unsigned* __restrict__ X2,
                                                  const uint4* __restrict__ Twf,
                                                  const uint4* __restrict__ Thf) {
    __shared__ unsigned Z[256 * 64];     // 64 KB
    __shared__ unsigned P[4 * 16 * 32];  // 8 KB chunk: [c4][h16][w2]
    int tid = threadIdx.x;
    int lane = tid & 63, r = (tid >> 6) & 3, team = tid >> 8;
    int m = lane & 15, q = lane >> 4;
    int bt, c0;
    xcd_decode(blockIdx.x, bt, c0);
    int b = bt >> 4, t = bt & 15;
    const float* xs = x + (size_t)bt * 262144;   // (h,w,c) slab
    int hme = m >> 2, cme = m & 3;

    // twiddle fragment loads (replaces 96 sincosf/thread)
    U48 Are[2], Aim[2], Hre[4], Him[4];
#pragma unroll
    for (int ka = 0; ka < 2; ++ka) {
        Are[ka].u4 = Twf[((0 * 4 + r) * 2 + ka) * 64 + lane];
        Aim[ka].u4 = Twf[((1 * 4 + r) * 2 + ka) * 64 + lane];
    }
#pragma unroll
    for (int ka = 0; ka < 4; ++ka) {
        Hre[ka].u4 = Thf[((0 * 4 + r) * 4 + ka) * 64 + lane];
        Him[ka].u4 = Thf[((1 * 4 + r) * 4 + ka) * 64 + lane];
    }

    // preload ALL chunks: one pair-site (h, w2) per thread per chunk
    int s_h = tid >> 5;            // hloc 0..15
    int s_w2 = tid & 31;           // w2 0..31
    float4 f[4][2];
#pragma unroll
    for (int ch = 0; ch < 4; ++ch) {
        const float* pa = xs + (size_t)(ch * 16 + s_h) * 4096 + (size_t)s_w2 * 128 + c0;
        f[ch][0] = *(const float4*)pa;
        f[ch][1] = *(const float4*)(pa + 64);
    }

    for (int ch = 0; ch < 4; ++ch) {
        int h = ch * 16 + s_h;
        float a0[4] = {f[ch][0].x, f[ch][0].y, f[ch][0].z, f[ch][0].w};
        float a1[4] = {f[ch][1].x, f[ch][1].y, f[ch][1].z, f[ch][1].w};
#pragma unroll
        for (int j = 0; j < 4; ++j) {
            int w2s = s_w2 ^ ((((h & 3) ^ ((j & 1) << 1))) << 3);
            P[j * 512 + s_h * 32 + w2s] = bfpack(make_float2(a0[j], a1[j]));
        }
        __syncthreads();
        // compute: 4 g-groups this chunk (2 per team); g covers 4 h x 4 c
#pragma unroll
        for (int gi = 0; gi < 2; ++gi) {
            int g = ch * 4 + gi * 2 + team;
            int h2 = g * 4 + hme;
            int hl2 = h2 & 15;
            int swz = ((h2 & 3) ^ ((cme & 1) << 1)) << 3;
            U48 B[2];
#pragma unroll
            for (int ka = 0; ka < 2; ++ka) {
                int w2a = (ka * 16 + q * 4) ^ swz;
                B[ka].u4 = *(const uint4*)&P[cme * 512 + hl2 * 32 + w2a];
            }
            f32x4 ar = {0.f, 0.f, 0.f, 0.f}, ai = {0.f, 0.f, 0.f, 0.f};
#pragma unroll
            for (int ka = 0; ka < 2; ++ka) {
                ar = __builtin_amdgcn_mfma_f32_16x16x32_bf16(Are[ka].v8, B[ka].v8, ar, 0, 0, 0);
                ai = __builtin_amdgcn_mfma_f32_16x16x32_bf16(Aim[ka].v8, B[ka].v8, ai, 0, 0, 0);
            }
#pragma unroll
            for (int reg = 0; reg < 4; ++reg) {
                int wpp = r * 16 + q * 4 + reg;
                Z[zidx(wpp * 4 + cme, h2)] = bfpack(make_float2(ar[reg], ai[reg]));
            }
        }
        __syncthreads();
    }

    // stage 2: H-DFT (cpx K=128) from Z -> X2
    size_t ob = (size_t)b * 4194304 + (size_t)t * 64 + (c0 + cme);
#pragma unroll 2
    for (int gi = 0; gi < 8; ++gi) {
        int g = gi * 2 + team;
        int col = g * 16 + m;          // = w*4 + cL
        int w = g * 4 + hme;
        U48 B[4];
#pragma unroll
        for (int ka = 0; ka < 4; ++ka) {
            int h0 = ka * 16 + q * 4;
            int zi = zidx(col, h0);
            B[ka].u2[0] = *(const uint2*)&Z[zi];
            B[ka].u2[1] = *(const uint2*)&Z[zi + 2];
        }
        f32x4 ar = {0.f, 0.f, 0.f, 0.f}, ai = {0.f, 0.f, 0.f, 0.f};
#pragma unroll
        for (int ka = 0; ka < 4; ++ka) {
            ar = __builtin_amdgcn_mfma_f32_16x16x32_bf16(Hre[ka].v8, B[ka].v8, ar, 0, 0, 0);
            ai = __builtin_amdgcn_mfma_f32_16x16x32_bf16(Him[ka].v8, B[ka].v8, ai, 0, 0, 0);
        }
#pragma unroll
        for (int reg = 0; reg < 4; ++reg) {
            int hp = r * 16 + q * 4 + reg;
            X2[ob + (size_t)hp * 65536 + (size_t)w * 1024] = bfpack(make_float2(ar[reg], ai[reg]));
        }
    }
}

// ---------------------------------------------------------------------------
// K3: fused inverse 2D DFT. wg = (b,t,c4): grid 512. Twiddles from tables.
// Stage 1: H-inv -> Z[(h'*4+c)][w]. Stage 2: W-inv (real out) -> out fp32.
// ---------------------------------------------------------------------------
__global__ __launch_bounds__(512, 4) void k_inv2d(const unsigned* __restrict__ X3,
                                                  float* __restrict__ out,
                                                  const uint4* __restrict__ Thi,
                                                  const uint4* __restrict__ Twi) {
    __shared__ unsigned Z[256 * 64];     // 64 KB
    __shared__ unsigned P[4 * 8 * 64];   // 8 KB chunk: [c4][w8][h64]
    int tid = threadIdx.x;
    int lane = tid & 63, r = (tid >> 6) & 3, team = tid >> 8;
    int m = lane & 15, q = lane >> 4;
    int bt, c0;
    xcd_decode(blockIdx.x, bt, c0);
    const unsigned* xs = X3 + (size_t)bt * 262144;   // (w,h,c) slab
    int hme = m >> 2, cme = m & 3;

    // twiddle fragment loads
    U48 Hre[4], Him[4], Wre[4];
#pragma unroll
    for (int ka = 0; ka < 4; ++ka) {
        Hre[ka].u4 = Thi[((0 * 4 + r) * 4 + ka) * 64 + lane];
        Him[ka].u4 = Thi[((1 * 4 + r) * 4 + ka) * 64 + lane];
        Wre[ka].u4 = Twi[(r * 4 + ka) * 64 + lane];
    }

    // preload ALL chunks: one (w,h) site per thread per chunk
    int s_wl = tid >> 6;           // 0..7
    int s_hh = tid & 63;           // 0..63
    uint4 d[8];
#pragma unroll
    for (int cw = 0; cw < 8; ++cw)
        d[cw] = *(const uint4*)(xs + (size_t)(cw * 8 + s_wl) * 4096 + (size_t)s_hh * 64 + c0);

    for (int cw = 0; cw < 8; ++cw) {
        unsigned dd[4] = {d[cw].x, d[cw].y, d[cw].z, d[cw].w};
#pragma unroll
        for (int j = 0; j < 4; ++j) {
            int hs = s_hh ^ ((((s_wl & 3) ^ ((j & 1) << 1))) << 3);
            P[j * 512 + s_wl * 64 + hs] = dd[j];
        }
        __syncthreads();
        // compute: 2 g-groups this chunk (1 per team); g covers 4 w x 4 c
        {
            int g = cw * 2 + team;
            int w = g * 4 + hme;
            int wl = w & 7;
            int swz = ((wl & 3) ^ ((cme & 1) << 1)) << 3;
            U48 B[4];
#pragma unroll
            for (int ka = 0; ka < 4; ++ka) {
                int ha = (ka * 16 + q * 4) ^ swz;
                B[ka].u4 = *(const uint4*)&P[cme * 512 + wl * 64 + ha];
            }
            f32x4 ar = {0.f, 0.f, 0.f, 0.f}, ai = {0.f, 0.f, 0.f, 0.f};
#pragma unroll
            for (int ka = 0; ka < 4; ++ka) {
                ar = __builtin_amdgcn_mfma_f32_16x16x32_bf16(Hre[ka].v8, B[ka].v8, ar, 0, 0, 0);
                ai = __builtin_amdgcn_mfma_f32_16x16x32_bf16(Him[ka].v8, B[ka].v8, ai, 0, 0, 0);
            }
#pragma unroll
            for (int reg = 0; reg < 4; ++reg) {
                int hp = r * 16 + q * 4 + reg;
                Z[zidx(hp * 4 + cme, w)] = bfpack(make_float2(ar[reg], ai[reg]));
            }
        }
        __syncthreads();
    }

    // stage 2: W-inv (real out)
#pragma unroll 2
    for (int gi = 0; gi < 8; ++gi) {
        int g = gi * 2 + team;
        int col = g * 16 + m;          // = h*4 + cL
        int h = g * 4 + hme;
        U48 B[4];
#pragma unroll
        for (int ka = 0; ka < 4; ++ka) {
            int w0 = ka * 16 + q * 4;
            int zi = zidx(col, w0);
            B[ka].u2[0] = *(const uint2*)&Z[zi];
            B[ka].u2[1] = *(const uint2*)&Z[zi + 2];
        }
        f32x4 ar = {0.f, 0.f, 0.f, 0.f};
#pragma unroll
        for (int ka = 0; ka < 4; ++ka)
            ar = __builtin_amdgcn_mfma_f32_16x16x32_bf16(Wre[ka].v8, B[ka].v8, ar, 0, 0, 0);
        float* dst = out + (size_t)bt * 262144 + (size_t)h * 4096 + (c0 + cme);
#pragma unroll
        for (int reg = 0; reg < 4; ++reg) {
            int wpp = r * 16 + q * 4 + reg;
            dst[(size_t)wpp * 64] = ar[reg];
        }
    }
}

// ---------------------------------------------------------------------------
// K2 (mid): unchanged (verified R4..R8). FFT-16 fwd along T + gates + MFMA
// delta-matmul + scan + FFT-16 inv. X2 (b,h,w,t,c) -> X3 (b,t,w,h,c).
// ---------------------------------------------------------------------------
__global__ __launch_bounds__(256) void k_mid(
    const float* __restrict__ x, const unsigned* __restrict__ X2,
    unsigned* __restrict__ X3,
    const float* __restrict__ Ak, const float* __restrict__ Bk,
    const float* __restrict__ fb, const float* __restrict__ fs,
    const float* __restrict__ ib, const float* __restrict__ isc_,
    const float* __restrict__ dW, const float* __restrict__ db) {
    const float CT[16] = {1.f, 0.9238795f, 0.7071068f, 0.3826834f, 0.f, -0.3826834f,
                          -0.7071068f, -0.9238795f, -1.f, -0.9238795f, -0.7071068f,
                          -0.3826834f, 0.f, 0.3826834f, 0.7071068f, 0.9238795f};
    const float SN[16] = {0.f, 0.3826834f, 0.7071068f, 0.9238795f, 1.f, 0.9238795f,
                          0.7071068f, 0.3826834f, 0.f, -0.3826834f, -0.7071068f,
                          -0.9238795f, -1.f, -0.9238795f, -0.7071068f, -0.3826834f};
    __shared__ float Akl[1728], Bkl[1728];
    __shared__ __align__(16) float xs[4][16 * 68 + 4];

    int tid = threadIdx.x;
    int g = tid >> 6, lane = tid & 63;
    int c = lane;
    int m = lane & 15, q = lane >> 4;
    int site = blockIdx.x * 4 + g;
    int b = site >> 12, hw = site & 4095;
    int h = hw >> 6, w = hw & 63;
    size_t base = (size_t)b * SB_ + (size_t)hw * 64;

    for (int i = tid; i < 1728; i += 256) { Akl[i] = Ak[i]; Bkl[i] = Bk[i]; }

    // delta-W MFMA B-fragments in-register
    U48 Ub[4][2];
#pragma unroll
    for (int nt = 0; nt < 4; ++nt)
#pragma unroll
        for (int ka = 0; ka < 2; ++ka)
#pragma unroll
            for (int p2 = 0; p2 < 4; ++p2) {
                int kb = ka * 32 + q * 8 + 2 * p2;
                int ccol = m + 16 * nt;
                Ub[nt][ka].u[p2] = bfpack(make_float2(dW[kb * 64 + ccol], dW[(kb + 1) * 64 + ccol]));
            }

    float xv[16];
    float2 v[16];
    const unsigned* src2 = X2 + (size_t)site * 1024;
#pragma unroll
    for (int t = 0; t < 16; ++t) {
        xv[t] = x[base + (size_t)t * ST_ + c];
        v[t] = bfunpack(src2[t * 64 + c]);
    }
#pragma unroll
    for (int t = 0; t < 16; ++t) xs[g][t * 68 + c] = xv[t];
    __syncthreads();

    // MFMA delta matmul
    bf16x8 Afrag[2];
#pragma unroll
    for (int ka = 0; ka < 2; ++ka) {
        int d0 = ka * 32 + q * 8;
        const float* p = &xs[g][m * 68 + d0];
        float4 f0 = *(const float4*)p;
        float4 f1 = *(const float4*)(p + 4);
        union { bf16x8 v8; unsigned uu[4]; } U;
        U.uu[0] = bfpack(make_float2(f0.x, f0.y));
        U.uu[1] = bfpack(make_float2(f0.z, f0.w));
        U.uu[2] = bfpack(make_float2(f1.x, f1.y));
        U.uu[3] = bfpack(make_float2(f1.z, f1.w));
        Afrag[ka] = U.v8;
    }
#pragma unroll
    for (int nt = 0; nt < 4; ++nt) {
        int ccol = m + 16 * nt;
        float dbn = db[ccol];
        f32x4 acc = {dbn, dbn, dbn, dbn};
#pragma unroll
        for (int ka = 0; ka < 2; ++ka)
            acc = __builtin_amdgcn_mfma_f32_16x16x32_bf16(Afrag[ka], Ub[nt][ka].v8, acc, 0, 0, 0);
#pragma unroll
        for (int reg = 0; reg < 4; ++reg)
            xs[g][(q * 4 + reg) * 68 + ccol] = acc[reg];
    }

    // A_f/B_f generators from the 27 taps
    float sh, ch; sincosf(TWO_PI * (float)h / 64.0f, &sh, &ch);
    float sw, cw; sincosf(TWO_PI * (float)w / 64.0f, &sw, &cw);
    float2 eh[3] = { make_float2(ch, sh), make_float2(1.f, 0.f), make_float2(ch, -sh) };
    float2 ew[3] = { make_float2(cw, sw), make_float2(1.f, 0.f), make_float2(cw, -sw) };
    float2 GA[3], GB[3];
#pragma unroll
    for (int kt = 0; kt < 3; ++kt) { GA[kt] = make_float2(0.f, 0.f); GB[kt] = make_float2(0.f, 0.f); }
#pragma unroll
    for (int kh = 0; kh < 3; ++kh) {
#pragma unroll
        for (int kw = 0; kw < 3; ++kw) {
            float2 e = cmul(eh[kh], ew[kw]);
#pragma unroll
            for (int kt = 0; kt < 3; ++kt) {
                float ka = Akl[c * 27 + kt * 9 + kh * 3 + kw];
                float kb = Bkl[c * 27 + kt * 9 + kh * 3 + kw];
                GA[kt].x = fmaf(ka, e.x, GA[kt].x);
                GA[kt].y = fmaf(ka, e.y, GA[kt].y);
                GB[kt].x = fmaf(kb, e.x, GB[kt].x);
                GB[kt].y = fmaf(kb, e.y, GB[kt].y);
            }
        }
    }
    float fbc = fb[c], fsc = fs[c], ibc = ib[c], iscv = isc_[c];

    fft16<-1>(v);
    __syncthreads();

    float delta_raw[16];
#pragma unroll
    for (int t = 0; t < 16; ++t) delta_raw[t] = xs[g][t * 68 + c];

    float2 hv = make_float2(0.f, 0.f);
#pragma unroll
    for (int t = 0; t < 16; ++t) {
        float ct = CT[t], st = SN[t];
        float2 Af, Bf;
        Af.x = GA[1].x + ct * (GA[0].x + GA[2].x) - st * (GA[0].y - GA[2].y);
        Af.y = GA[1].y + ct * (GA[0].y + GA[2].y) + st * (GA[0].x - GA[2].x);
        Bf.x = GB[1].x + ct * (GB[0].x + GB[2].x) - st * (GB[0].y - GB[2].y);
        Bf.y = GB[1].y + ct * (GB[0].y + GB[2].y) + st * (GB[0].x - GB[2].x);

        float xc = xv[t];
        float fg  = __builtin_amdgcn_rcpf(1.f + __expf(-(fbc + fsc * xc)));
        float igv = __builtin_amdgcn_rcpf(1.f + __expf(-(ibc + iscv * xc)));
        float dot = delta_raw[t];
        float delta = (dot > 20.f) ? dot : __logf(1.f + __expf(dot));

        float sR = igv * delta;
        float2 bbv;
        bbv.x = sR * (Bf.x * v[t].x - Bf.y * v[t].y);
        bbv.y = sR * (Bf.x * v[t].y + Bf.y * v[t].x);
        float2 av = make_float2(fg * Af.x, fg * Af.y);
        float2 nh;
        nh.x = av.x * hv.x - av.y * hv.y + bbv.x;
        nh.y = av.x * hv.y + av.y * hv.x + bbv.y;
        hv = nh;
        v[t] = hv;
    }

    fft16<1>(v);

    // write X3 (b,t,w,h,c)
    size_t ob = (size_t)b * 4194304 + (size_t)w * 4096 + (size_t)h * 64 + c;
#pragma unroll
    for (int t = 0; t < 16; ++t) {
        float2 o = make_float2(v[t].x * 0.0625f, v[t].y * 0.0625f);
        X3[ob + (size_t)t * 262144] = bfpack(o);
    }
}

extern "C" void kernel_launch(void* const* d_in, const int* in_sizes, int n_in,
                              void* d_out, int out_size, void* d_ws, size_t ws_size,
                              hipStream_t stream) {
    const float* x   = (const float*)d_in[0];
    const float* Ak  = (const float*)d_in[1];
    const float* Bk  = (const float*)d_in[2];
    const float* fb  = (const float*)d_in[3];
    const float* fs  = (const float*)d_in[4];
    const float* ib  = (const float*)d_in[5];
    const float* is_ = (const float*)d_in[6];
    const float* dW  = (const float*)d_in[7];
    const float* db  = (const float*)d_in[8];
    float* out = (float*)d_out;
    unsigned* ws = (unsigned*)d_ws;
    unsigned* X2 = ws + BUF_A;
    unsigned* X3 = ws + BUF_B;

    k_setup<<<104, 256, 0, stream>>>(dW, ws);
    k_fwd2d<<<Bb * Tt * 16, 512, 0, stream>>>(x, X2,
                                              (const uint4*)(ws + OFF_TWF),
                                              (const uint4*)(ws + OFF_THF));
    k_mid<<<(Bb * Hh * Ww) / 4, 256, 0, stream>>>(x, X2, X3, Ak, Bk, fb, fs, ib, is_, dW, db);
    k_inv2d<<<Bb * Tt * 16, 512, 0, stream>>>(X3, out,
                                              (const uint4*)(ws + OFF_THI),
                                              (const uint4*)(ws + OFF_TWI));
}